// Round 1
// baseline (4872.638 us; speedup 1.0000x reference)
//
#include <hip/hip_runtime.h>
#include <cstddef>

#define B_    64
#define P_    196
#define E_    2048
#define H_    512
#define EMB_  512
#define V_    10000
#define TCAP_ 50
#define TMAX_ 49
#define KI_   2560   // E_ + EMB_
#define G3_   1536   // 3*H_
#define GIP_  (B_*G3_)

typedef __attribute__((ext_vector_type(8))) short short8;
typedef __attribute__((ext_vector_type(4))) float floatx4;

__device__ __forceinline__ unsigned short f2bf_rne(float f) {
    unsigned int x = __float_as_uint(f);
    unsigned int r = (x + 0x7fffu + ((x >> 16) & 1u)) >> 16;
    return (unsigned short)r;
}
__device__ __forceinline__ float bf2f(unsigned int u16) {
    return __uint_as_float(u16 << 16);
}
__device__ __forceinline__ float fast_tanh(float x) {
    float a = fabsf(x);
    float e = __expf(2.0f * a);
    float r = 1.0f - 2.0f / (e + 1.0f);
    return (x < 0.0f) ? -r : r;
}
__device__ __forceinline__ float fast_sig(float x) {
    return 1.0f / (1.0f + __expf(-x));
}

// ---------------- output init: zero t=49 slices, write dec ----------------
__global__ void init_out_kernel(float* __restrict__ preds, float* __restrict__ alphas,
                                float* __restrict__ dec, const int* __restrict__ lens)
{
    int i = blockIdx.x * 256 + threadIdx.x;   // 0 .. 639999
    if (i < B_ * V_) {
        int b = i / V_, v = i - b * V_;
        preds[((size_t)b * TCAP_ + TMAX_) * V_ + v] = 0.f;
    }
    if (i < B_ * P_) {
        int b = i / P_, p = i - b * P_;
        alphas[((size_t)b * TCAP_ + TMAX_) * P_ + p] = 0.f;
    }
    if (i < B_) dec[i] = (float)(lens[i] - 1);
}

// ---------------- f32 -> bf16 cast (4 elems/thread) ----------------
__global__ void f2bf_kernel(const float* __restrict__ src, unsigned short* __restrict__ dst, int n4)
{
    int i = blockIdx.x * 256 + threadIdx.x;
    if (i >= n4) return;
    float4 v = ((const float4*)src)[i];
    uint2 o;
    o.x = (unsigned)f2bf_rne(v.x) | ((unsigned)f2bf_rne(v.y) << 16);
    o.y = (unsigned)f2bf_rne(v.z) | ((unsigned)f2bf_rne(v.w) << 16);
    ((uint2*)dst)[i] = o;
}

// ---------------- mean over P, output bf16 (64 x 2048) ----------------
__global__ void mean_kernel(const float* __restrict__ f, unsigned short* __restrict__ out)
{
    int i = blockIdx.x * 256 + threadIdx.x;   // 0..131071
    int b = i >> 11, e = i & 2047;
    const float* p = f + (size_t)b * P_ * E_ + e;
    float s = 0.f;
    #pragma unroll 4
    for (int k = 0; k < P_; ++k) s += p[(size_t)k * E_];
    out[i] = f2bf_rne(s * (1.0f / (float)P_));
}

// ---------------- big MFMA GEMM: xwx = features(bf16) @ Wx^T, bf16 out ----------------
// grid (196, 32), block 256 = 4 waves; block tile 64(m) x 64(n); wave: 16m x 64n
__global__ void __launch_bounds__(256)
mfma_xwx_kernel(const unsigned short* __restrict__ A,   // 12544 x 2048 bf16
                const unsigned short* __restrict__ W,   // 2048 x 2048 bf16
                const float* __restrict__ bias,
                unsigned short* __restrict__ C)         // 12544 x 2048 bf16
{
    int wv = threadIdx.x >> 6, lane = threadIdx.x & 63;
    int mr = lane & 15, quad = lane >> 4;
    int m0 = blockIdx.x * 64 + wv * 16;
    int n0 = blockIdx.y * 64;
    const unsigned short* pa = A + (size_t)(m0 + mr) * E_ + quad * 8;
    const unsigned short* pw = W + (size_t)(n0 + mr) * E_ + quad * 8;
    floatx4 acc[4] = {{0.f,0.f,0.f,0.f},{0.f,0.f,0.f,0.f},{0.f,0.f,0.f,0.f},{0.f,0.f,0.f,0.f}};
    #pragma unroll 8
    for (int k0 = 0; k0 < E_; k0 += 32) {
        short8 a = *(const short8*)(const void*)(pa + k0);
        #pragma unroll
        for (int r = 0; r < 4; ++r) {
            short8 b = *(const short8*)(const void*)(pw + (size_t)r * 16 * E_ + k0);
            acc[r] = __builtin_amdgcn_mfma_f32_16x16x32_bf16(a, b, acc[r], 0, 0, 0);
        }
    }
    #pragma unroll
    for (int r = 0; r < 4; ++r) {
        int col = n0 + r * 16 + mr;
        float bs = bias[col];
        #pragma unroll
        for (int i = 0; i < 4; ++i) {
            int row = m0 + quad * 4 + i;
            C[(size_t)row * E_ + col] = f2bf_rne(acc[r][i] + bs);
        }
    }
}

// ---------------- skinny MFMA GEMM: C[64, N] = A[64,K] @ W[N,K]^T (+bias) ----------------
// block 256 = 4 waves stacked on m (4 x 16 = 64 rows); blockIdx.x = n-tile (16 wide),
// blockIdx.y = K-split chunk (writes partial C at offset y*64*ldc; bias only on y==0).
template<int KC>
__global__ void __launch_bounds__(256)
mfma_gemm64(const unsigned short* __restrict__ A, int ld,
            const unsigned short* __restrict__ W,
            const float* __restrict__ bias,
            float* __restrict__ C, unsigned short* __restrict__ Cbf,
            int ldc, const int* __restrict__ lens, int t)
{
    int wv = threadIdx.x >> 6, lane = threadIdx.x & 63;
    int mr = lane & 15, quad = lane >> 4;
    int m0 = wv * 16;
    int n0 = blockIdx.x * 16;
    int koff = blockIdx.y * KC;
    C += (size_t)blockIdx.y * 64 * ldc;
    const unsigned short* pa = A + (size_t)(m0 + mr) * ld + koff + quad * 8;
    const unsigned short* pb = W + (size_t)(n0 + mr) * ld + koff + quad * 8;
    floatx4 acc = {0.f, 0.f, 0.f, 0.f};
    #pragma unroll 16
    for (int k0 = 0; k0 < KC; k0 += 32) {
        short8 a = *(const short8*)(const void*)(pa + k0);
        short8 b = *(const short8*)(const void*)(pb + k0);
        acc = __builtin_amdgcn_mfma_f32_16x16x32_bf16(a, b, acc, 0, 0, 0);
    }
    int col = n0 + mr;
    float bs = (bias && blockIdx.y == 0) ? bias[col] : 0.f;
    #pragma unroll
    for (int i = 0; i < 4; ++i) {
        int row = m0 + quad * 4 + i;
        float v = acc[i] + bs;
        if (lens && lens[row] <= t) v = 0.f;
        C[(size_t)row * ldc + col] = v;
        if (Cbf) Cbf[(size_t)row * ldc + col] = f2bf_rne(v);
    }
}

// ---------------- fused h-projections: hwh (2048), hf (2048), gh (1536); K=512 ----------------
__global__ void __launch_bounds__(256)
mfma_h3(const unsigned short* __restrict__ hbf,
        const unsigned short* __restrict__ whbf, const float* __restrict__ Wh_b,
        const unsigned short* __restrict__ fbbf, const float* __restrict__ fb_b,
        const unsigned short* __restrict__ ghhbf, const float* __restrict__ ghh_b,
        float* __restrict__ hwh, float* __restrict__ hf, float* __restrict__ gh)
{
    int bt = blockIdx.x;   // 0..351
    const unsigned short* W; const float* bias; float* C; int n0; int ldc;
    if (bt < 128)      { W = whbf;  bias = Wh_b;  C = hwh; n0 = bt * 16;         ldc = E_; }
    else if (bt < 256) { W = fbbf;  bias = fb_b;  C = hf;  n0 = (bt - 128) * 16; ldc = E_; }
    else               { W = ghhbf; bias = ghh_b; C = gh;  n0 = (bt - 256) * 16; ldc = G3_; }
    int wv = threadIdx.x >> 6, lane = threadIdx.x & 63;
    int mr = lane & 15, quad = lane >> 4;
    int m0 = wv * 16;
    const unsigned short* pa = hbf + (size_t)(m0 + mr) * H_ + quad * 8;
    const unsigned short* pb = W + (size_t)(n0 + mr) * H_ + quad * 8;
    floatx4 acc = {0.f, 0.f, 0.f, 0.f};
    #pragma unroll
    for (int k0 = 0; k0 < H_; k0 += 32) {
        short8 a = *(const short8*)(const void*)(pa + k0);
        short8 b = *(const short8*)(const void*)(pb + k0);
        acc = __builtin_amdgcn_mfma_f32_16x16x32_bf16(a, b, acc, 0, 0, 0);
    }
    int col = n0 + mr;
    float bs = bias[col];
    #pragma unroll
    for (int i = 0; i < 4; ++i) {
        int row = m0 + quad * 4 + i;
        C[(size_t)row * ldc + col] = acc[i] + bs;
    }
}

// ---------------- lam[b,p] = sum_e tanh(xwx[b,p,e] + hwh[b,e]) * Vw[e] + Vb ----------------
// 4 waves/block, 1 row per wave; grid 3136
__global__ void __launch_bounds__(256)
lam_kernel(const unsigned short* __restrict__ xwx, const float* __restrict__ hwh,
           const float* __restrict__ Vw, const float* __restrict__ Vb,
           float* __restrict__ lam)
{
    int row = blockIdx.x * 4 + (threadIdx.x >> 6);   // 0..12543
    int lane = threadIdx.x & 63;
    int b = row / P_;
    const unsigned short* px = xwx + (size_t)row * E_;
    const float* ph = hwh + (size_t)b * E_;
    float acc = 0.f;
    #pragma unroll
    for (int it = 0; it < 4; ++it) {
        int e = it * 512 + lane * 8;
        uint4 u = *(const uint4*)(const void*)(px + e);
        float4 h0 = *(const float4*)(ph + e);
        float4 h1 = *(const float4*)(ph + e + 4);
        float4 v0 = *(const float4*)(Vw + e);
        float4 v1 = *(const float4*)(Vw + e + 4);
        acc = fmaf(fast_tanh(bf2f(u.x & 0xffffu) + h0.x), v0.x, acc);
        acc = fmaf(fast_tanh(bf2f(u.x >> 16)     + h0.y), v0.y, acc);
        acc = fmaf(fast_tanh(bf2f(u.y & 0xffffu) + h0.z), v0.z, acc);
        acc = fmaf(fast_tanh(bf2f(u.y >> 16)     + h0.w), v0.w, acc);
        acc = fmaf(fast_tanh(bf2f(u.z & 0xffffu) + h1.x), v1.x, acc);
        acc = fmaf(fast_tanh(bf2f(u.z >> 16)     + h1.y), v1.y, acc);
        acc = fmaf(fast_tanh(bf2f(u.w & 0xffffu) + h1.z), v1.z, acc);
        acc = fmaf(fast_tanh(bf2f(u.w >> 16)     + h1.w), v1.w, acc);
    }
    #pragma unroll
    for (int off = 32; off > 0; off >>= 1) acc += __shfl_down(acc, off);
    if (lane == 0) lam[row] = acc + Vb[0];
}

// ---------------- softmax over p, z = sum_p alpha*f, gate, write inp(bf16) + alphas ----------------
// grid (5, 64): tiles 0..3 = 512-wide z/gate chunks; tile 4 = embedding copy
__global__ void __launch_bounds__(256)
attn_z_kernel(const unsigned short* __restrict__ fbf, const float* __restrict__ lam,
              const float* __restrict__ hf, const float* __restrict__ embed_w,
              const int* __restrict__ captions, const int* __restrict__ lens,
              unsigned short* __restrict__ inpbf, float* __restrict__ alphas, int t)
{
    int b = blockIdx.y;
    int tile = blockIdx.x;
    int tid = threadIdx.x;
    if (tile == 4) {   // embedding -> inp[2048:2560]
        int cap = captions[b * TCAP_ + t];
        const float* e = embed_w + (size_t)cap * EMB_;
        int c = tid * 2;
        float2 v = *(const float2*)(e + c);
        *(unsigned int*)(inpbf + (size_t)b * KI_ + E_ + c) =
            (unsigned)f2bf_rne(v.x) | ((unsigned)f2bf_rne(v.y) << 16);
        return;
    }
    __shared__ float sa[256];
    __shared__ float sr[256];
    float x = (tid < P_) ? lam[b * P_ + tid] : -1e30f;
    sr[tid] = x;
    __syncthreads();
    for (int s = 128; s > 0; s >>= 1) {
        if (tid < s) sr[tid] = fmaxf(sr[tid], sr[tid + s]);
        __syncthreads();
    }
    float mx = sr[0];
    __syncthreads();
    float ex = (tid < P_) ? __expf(x - mx) : 0.f;
    sa[tid] = ex;
    sr[tid] = ex;
    __syncthreads();
    for (int s = 128; s > 0; s >>= 1) {
        if (tid < s) sr[tid] += sr[tid + s];
        __syncthreads();
    }
    float inv = 1.0f / sr[0];
    if (tile == 0 && tid < P_) {
        alphas[(size_t)b * TCAP_ * P_ + (size_t)t * P_ + tid] = (lens[b] > t) ? ex * inv : 0.f;
    }
    // z over this 512-wide chunk (2 e per thread)
    int e0 = tile * 512 + tid * 2;
    const unsigned short* fp = fbf + (size_t)b * P_ * E_ + e0;
    float a0 = 0.f, a1 = 0.f;
    #pragma unroll 4
    for (int p = 0; p < P_; ++p) {
        unsigned int u = *(const unsigned int*)(const void*)(fp + (size_t)p * E_);
        float ap = sa[p];
        a0 = fmaf(ap, bf2f(u & 0xffffu), a0);
        a1 = fmaf(ap, bf2f(u >> 16), a1);
    }
    a0 *= inv; a1 *= inv;
    float2 gv = *(const float2*)(hf + (size_t)b * E_ + e0);
    float g0 = fast_sig(gv.x), g1 = fast_sig(gv.y);
    *(unsigned int*)(inpbf + (size_t)b * KI_ + e0) =
        (unsigned)f2bf_rne(g0 * a0) | ((unsigned)f2bf_rne(g1 * a1) << 16);
}

// ---------------- GRU combine: h update (f32 + bf16 copies) ----------------
__global__ void gru_kernel(const float* __restrict__ gip, const float* __restrict__ gh,
                           const int* __restrict__ lens, float* __restrict__ h,
                           unsigned short* __restrict__ hbf, int t)
{
    int i = blockIdx.x * 256 + threadIdx.x;   // 0..32767
    int b = i >> 9, j = i & 511;
    size_t base = (size_t)b * G3_ + j;
    float ir = gip[base]        + gip[GIP_ + base]        + gip[2*GIP_ + base]        + gip[3*GIP_ + base];
    float iz = gip[base + 512]  + gip[GIP_ + base + 512]  + gip[2*GIP_ + base + 512]  + gip[3*GIP_ + base + 512];
    float in_= gip[base + 1024] + gip[GIP_ + base + 1024] + gip[2*GIP_ + base + 1024] + gip[3*GIP_ + base + 1024];
    float hr = gh[base], hz = gh[base + 512], hn = gh[base + 1024];
    float r  = fast_sig(ir + hr);
    float zg = fast_sig(iz + hz);
    float n  = fast_tanh(in_ + r * hn);
    float hp = h[i];
    float hv = (1.f - zg) * n + zg * hp;
    float ho = (lens[b] > t) ? hv : hp;
    h[i] = ho;
    hbf[i] = f2bf_rne(ho);
}

extern "C" void kernel_launch(void* const* d_in, const int* in_sizes, int n_in,
                              void* d_out, int out_size, void* d_ws, size_t ws_size,
                              hipStream_t stream)
{
    const float* features  = (const float*)d_in[0];
    const int*   captions  = (const int*)d_in[1];
    const int*   lengths   = (const int*)d_in[2];
    const float* Wx_w      = (const float*)d_in[3];
    const float* Wx_b      = (const float*)d_in[4];
    const float* Wh_w      = (const float*)d_in[5];
    const float* Wh_b      = (const float*)d_in[6];
    const float* V_w       = (const float*)d_in[7];
    const float* V_b       = (const float*)d_in[8];
    const float* init_h_w  = (const float*)d_in[9];
    const float* init_h_b  = (const float*)d_in[10];
    const float* f_beta_w  = (const float*)d_in[11];
    const float* f_beta_b  = (const float*)d_in[12];
    const float* embed_w   = (const float*)d_in[13];
    const float* gru_w_ih  = (const float*)d_in[14];
    const float* gru_b_ih  = (const float*)d_in[15];
    const float* gru_w_hh  = (const float*)d_in[16];
    const float* gru_b_hh  = (const float*)d_in[17];
    const float* fc1_w     = (const float*)d_in[18];
    const float* fc1_b     = (const float*)d_in[19];

    float* preds  = (float*)d_out;
    float* alphas = preds + (size_t)B_ * TCAP_ * V_;
    float* dec    = alphas + (size_t)B_ * TCAP_ * P_;

    char* w = (char*)d_ws;
    unsigned short* fbf     = (unsigned short*)w; w += (size_t)12544 * 2048 * 2;
    unsigned short* xwx     = (unsigned short*)w; w += (size_t)12544 * 2048 * 2;
    unsigned short* wxbf    = (unsigned short*)w; w += (size_t)2048 * 2048 * 2;
    unsigned short* whbf    = (unsigned short*)w; w += (size_t)2048 * 512 * 2;
    unsigned short* fbbf    = (unsigned short*)w; w += (size_t)2048 * 512 * 2;
    unsigned short* ghhbf   = (unsigned short*)w; w += (size_t)1536 * 512 * 2;
    unsigned short* wihbf   = (unsigned short*)w; w += (size_t)1536 * 2560 * 2;
    unsigned short* fc1bf   = (unsigned short*)w; w += (size_t)10000 * 512 * 2;
    unsigned short* ihwbf   = (unsigned short*)w; w += (size_t)512 * 2048 * 2;
    unsigned short* fmeanbf = (unsigned short*)w; w += (size_t)64 * 2048 * 2;
    unsigned short* hbf     = (unsigned short*)w; w += (size_t)64 * 512 * 2;
    unsigned short* inpbf   = (unsigned short*)w; w += (size_t)64 * KI_ * 2;
    float* h   = (float*)w; w += (size_t)64 * 512 * 4;
    float* hwh = (float*)w; w += (size_t)64 * 2048 * 4;
    float* hf  = (float*)w; w += (size_t)64 * 2048 * 4;
    float* gh  = (float*)w; w += (size_t)64 * 1536 * 4;
    float* gip = (float*)w; w += (size_t)4 * 64 * 1536 * 4;
    float* lam = (float*)w; w += (size_t)64 * 196 * 4;

    init_out_kernel<<<2500, 256, 0, stream>>>(preds, alphas, dec, lengths);

    f2bf_kernel<<<25088, 256, 0, stream>>>(features, fbf, 12544 * 2048 / 4);
    f2bf_kernel<<<4096, 256, 0, stream>>>(Wx_w, wxbf, 2048 * 2048 / 4);
    f2bf_kernel<<<1024, 256, 0, stream>>>(Wh_w, whbf, 2048 * 512 / 4);
    f2bf_kernel<<<1024, 256, 0, stream>>>(f_beta_w, fbbf, 2048 * 512 / 4);
    f2bf_kernel<<<768, 256, 0, stream>>>(gru_w_hh, ghhbf, 1536 * 512 / 4);
    f2bf_kernel<<<3840, 256, 0, stream>>>(gru_w_ih, wihbf, 1536 * 2560 / 4);
    f2bf_kernel<<<5000, 256, 0, stream>>>(fc1_w, fc1bf, 10000 * 512 / 4);
    f2bf_kernel<<<1024, 256, 0, stream>>>(init_h_w, ihwbf, 512 * 2048 / 4);

    mean_kernel<<<512, 256, 0, stream>>>(features, fmeanbf);
    // h0 = fmean @ init_h_w^T + b  (also writes hbf)
    mfma_gemm64<2048><<<dim3(32, 1), 256, 0, stream>>>(fmeanbf, 2048, ihwbf, init_h_b,
                                                       h, hbf, 512, nullptr, 0);
    // x_wx (bf16) = features @ Wx^T + b
    mfma_xwx_kernel<<<dim3(196, 32), 256, 0, stream>>>(fbf, wxbf, Wx_b, xwx);

    for (int t = 0; t < TMAX_; ++t) {
        mfma_h3<<<352, 256, 0, stream>>>(hbf, whbf, Wh_b, fbbf, f_beta_b, ghhbf, gru_b_hh,
                                         hwh, hf, gh);
        lam_kernel<<<3136, 256, 0, stream>>>(xwx, hwh, V_w, V_b, lam);
        attn_z_kernel<<<dim3(5, 64), 256, 0, stream>>>(fbf, lam, hf, embed_w, captions,
                                                       lengths, inpbf, alphas, t);
        // gi partials (K split 4 x 640)
        mfma_gemm64<640><<<dim3(96, 4), 256, 0, stream>>>(inpbf, KI_, wihbf, gru_b_ih,
                                                          gip, nullptr, G3_, nullptr, 0);
        gru_kernel<<<128, 256, 0, stream>>>(gip, gh, lengths, h, hbf, t);
        // preds[:, t, :] = h_new @ fc1^T + b  (masked)
        mfma_gemm64<512><<<dim3(625, 1), 256, 0, stream>>>(hbf, 512, fc1bf, fc1_b,
                                                           preds + (size_t)t * V_, nullptr,
                                                           TCAP_ * V_, lengths, t);
    }
}

// Round 2
// 4425.491 us; speedup vs baseline: 1.1010x; 1.1010x over previous
//
#include <hip/hip_runtime.h>
#include <cstddef>

#define B_    64
#define P_    196
#define E_    2048
#define H_    512
#define EMB_  512
#define V_    10000
#define TCAP_ 50
#define TMAX_ 49
#define KI_   2560   // E_ + EMB_
#define G3_   1536   // 3*H_

typedef __attribute__((ext_vector_type(8))) short short8;
typedef __attribute__((ext_vector_type(4))) float floatx4;

__device__ __forceinline__ unsigned short f2bf_rne(float f) {
    unsigned int x = __float_as_uint(f);
    unsigned int r = (x + 0x7fffu + ((x >> 16) & 1u)) >> 16;
    return (unsigned short)r;
}
__device__ __forceinline__ float bf2f(unsigned int u16) {
    return __uint_as_float(u16 << 16);
}
__device__ __forceinline__ float fast_tanh(float x) {
    float a = fabsf(x);
    float e = __expf(2.0f * a);
    float r = 1.0f - 2.0f / (e + 1.0f);
    return (x < 0.0f) ? -r : r;
}
__device__ __forceinline__ float fast_sig(float x) {
    return 1.0f / (1.0f + __expf(-x));
}

// ---------------- output init: zero t=49 slices, write dec ----------------
__global__ void init_out_kernel(float* __restrict__ preds, float* __restrict__ alphas,
                                float* __restrict__ dec, const int* __restrict__ lens)
{
    int i = blockIdx.x * 256 + threadIdx.x;
    if (i < B_ * V_) {
        int b = i / V_, v = i - b * V_;
        preds[((size_t)b * TCAP_ + TMAX_) * V_ + v] = 0.f;
    }
    if (i < B_ * P_) {
        int b = i / P_, p = i - b * P_;
        alphas[((size_t)b * TCAP_ + TMAX_) * P_ + p] = 0.f;
    }
    if (i < B_) dec[i] = (float)(lens[i] - 1);
}

// ---------------- f32 -> bf16 cast (4 elems/thread) ----------------
__global__ void f2bf_kernel(const float* __restrict__ src, unsigned short* __restrict__ dst, int n4)
{
    int i = blockIdx.x * 256 + threadIdx.x;
    if (i >= n4) return;
    float4 v = ((const float4*)src)[i];
    uint2 o;
    o.x = (unsigned)f2bf_rne(v.x) | ((unsigned)f2bf_rne(v.y) << 16);
    o.y = (unsigned)f2bf_rne(v.z) | ((unsigned)f2bf_rne(v.w) << 16);
    ((uint2*)dst)[i] = o;
}

// ---------------- mean over P, output bf16 (64 x 2048) ----------------
__global__ void mean_kernel(const float* __restrict__ f, unsigned short* __restrict__ out)
{
    int i = blockIdx.x * 256 + threadIdx.x;
    int b = i >> 11, e = i & 2047;
    const float* p = f + (size_t)b * P_ * E_ + e;
    float s = 0.f;
    #pragma unroll 4
    for (int k = 0; k < P_; ++k) s += p[(size_t)k * E_];
    out[i] = f2bf_rne(s * (1.0f / (float)P_));
}

// ---------------- big MFMA GEMM: xwx = features(bf16) @ Wx^T, bf16 out ----------------
__global__ void __launch_bounds__(256)
mfma_xwx_kernel(const unsigned short* __restrict__ A,
                const unsigned short* __restrict__ W,
                const float* __restrict__ bias,
                unsigned short* __restrict__ C)
{
    int wv = threadIdx.x >> 6, lane = threadIdx.x & 63;
    int mr = lane & 15, quad = lane >> 4;
    int m0 = blockIdx.x * 64 + wv * 16;
    int n0 = blockIdx.y * 64;
    const unsigned short* pa = A + (size_t)(m0 + mr) * E_ + quad * 8;
    const unsigned short* pw = W + (size_t)(n0 + mr) * E_ + quad * 8;
    floatx4 acc[4] = {{0.f,0.f,0.f,0.f},{0.f,0.f,0.f,0.f},{0.f,0.f,0.f,0.f},{0.f,0.f,0.f,0.f}};
    #pragma unroll 8
    for (int k0 = 0; k0 < E_; k0 += 32) {
        short8 a = *(const short8*)(const void*)(pa + k0);
        #pragma unroll
        for (int r = 0; r < 4; ++r) {
            short8 b = *(const short8*)(const void*)(pw + (size_t)r * 16 * E_ + k0);
            acc[r] = __builtin_amdgcn_mfma_f32_16x16x32_bf16(a, b, acc[r], 0, 0, 0);
        }
    }
    #pragma unroll
    for (int r = 0; r < 4; ++r) {
        int col = n0 + r * 16 + mr;
        float bs = bias[col];
        #pragma unroll
        for (int i = 0; i < 4; ++i) {
            int row = m0 + quad * 4 + i;
            C[(size_t)row * E_ + col] = f2bf_rne(acc[r][i] + bs);
        }
    }
}

// ---------------- skinny MFMA GEMM (used once for h0) ----------------
template<int KC>
__global__ void __launch_bounds__(256)
mfma_gemm64(const unsigned short* __restrict__ A, int ld,
            const unsigned short* __restrict__ W,
            const float* __restrict__ bias,
            float* __restrict__ C, unsigned short* __restrict__ Cbf, int ldc)
{
    int wv = threadIdx.x >> 6, lane = threadIdx.x & 63;
    int mr = lane & 15, quad = lane >> 4;
    int m0 = wv * 16;
    int n0 = blockIdx.x * 16;
    const unsigned short* pa = A + (size_t)(m0 + mr) * ld + quad * 8;
    const unsigned short* pb = W + (size_t)(n0 + mr) * ld + quad * 8;
    floatx4 acc = {0.f, 0.f, 0.f, 0.f};
    #pragma unroll 16
    for (int k0 = 0; k0 < KC; k0 += 32) {
        short8 a = *(const short8*)(const void*)(pa + k0);
        short8 b = *(const short8*)(const void*)(pb + k0);
        acc = __builtin_amdgcn_mfma_f32_16x16x32_bf16(a, b, acc, 0, 0, 0);
    }
    int col = n0 + mr;
    float bs = bias ? bias[col] : 0.f;
    #pragma unroll
    for (int i = 0; i < 4; ++i) {
        int row = m0 + quad * 4 + i;
        float v = acc[i] + bs;
        C[(size_t)row * ldc + col] = v;
        if (Cbf) Cbf[(size_t)row * ldc + col] = f2bf_rne(v);
    }
}

// ---------------- fused h-projections: hwh (2048), hf (2048), gh (1536); K=512 ----------------
__global__ void __launch_bounds__(256)
mfma_h3(const unsigned short* __restrict__ hbf,
        const unsigned short* __restrict__ whbf, const float* __restrict__ Wh_b,
        const unsigned short* __restrict__ fbbf, const float* __restrict__ fb_b,
        const unsigned short* __restrict__ ghhbf, const float* __restrict__ ghh_b,
        float* __restrict__ hwh, float* __restrict__ hf, float* __restrict__ gh)
{
    int bt = blockIdx.x;   // 0..351
    const unsigned short* W; const float* bias; float* C; int n0; int ldc;
    if (bt < 128)      { W = whbf;  bias = Wh_b;  C = hwh; n0 = bt * 16;         ldc = E_; }
    else if (bt < 256) { W = fbbf;  bias = fb_b;  C = hf;  n0 = (bt - 128) * 16; ldc = E_; }
    else               { W = ghhbf; bias = ghh_b; C = gh;  n0 = (bt - 256) * 16; ldc = G3_; }
    int wv = threadIdx.x >> 6, lane = threadIdx.x & 63;
    int mr = lane & 15, quad = lane >> 4;
    int m0 = wv * 16;
    const unsigned short* pa = hbf + (size_t)(m0 + mr) * H_ + quad * 8;
    const unsigned short* pb = W + (size_t)(n0 + mr) * H_ + quad * 8;
    floatx4 acc0 = {0.f, 0.f, 0.f, 0.f};
    floatx4 acc1 = {0.f, 0.f, 0.f, 0.f};
    #pragma unroll
    for (int k0 = 0; k0 < 256; k0 += 32) {   // 2-way K-split ILP
        short8 a0 = *(const short8*)(const void*)(pa + k0);
        short8 b0 = *(const short8*)(const void*)(pb + k0);
        acc0 = __builtin_amdgcn_mfma_f32_16x16x32_bf16(a0, b0, acc0, 0, 0, 0);
        short8 a1 = *(const short8*)(const void*)(pa + k0 + 256);
        short8 b1 = *(const short8*)(const void*)(pb + k0 + 256);
        acc1 = __builtin_amdgcn_mfma_f32_16x16x32_bf16(a1, b1, acc1, 0, 0, 0);
    }
    floatx4 acc = acc0 + acc1;
    int col = n0 + mr;
    float bs = bias[col];
    #pragma unroll
    for (int i = 0; i < 4; ++i) {
        int row = m0 + quad * 4 + i;
        C[(size_t)row * ldc + col] = acc[i] + bs;
    }
}

// ---------------- lam[b,p] = sum_e tanh(xwx[b,p,e] + hwh[b,e]) * Vw[e] + Vb ----------------
__global__ void __launch_bounds__(256)
lam_kernel(const unsigned short* __restrict__ xwx, const float* __restrict__ hwh,
           const float* __restrict__ Vw, const float* __restrict__ Vb,
           float* __restrict__ lam)
{
    int row = blockIdx.x * 4 + (threadIdx.x >> 6);
    int lane = threadIdx.x & 63;
    int b = row / P_;
    const unsigned short* px = xwx + (size_t)row * E_;
    const float* ph = hwh + (size_t)b * E_;
    float acc = 0.f;
    #pragma unroll
    for (int it = 0; it < 4; ++it) {
        int e = it * 512 + lane * 8;
        uint4 u = *(const uint4*)(const void*)(px + e);
        float4 h0 = *(const float4*)(ph + e);
        float4 h1 = *(const float4*)(ph + e + 4);
        float4 v0 = *(const float4*)(Vw + e);
        float4 v1 = *(const float4*)(Vw + e + 4);
        acc = fmaf(fast_tanh(bf2f(u.x & 0xffffu) + h0.x), v0.x, acc);
        acc = fmaf(fast_tanh(bf2f(u.x >> 16)     + h0.y), v0.y, acc);
        acc = fmaf(fast_tanh(bf2f(u.y & 0xffffu) + h0.z), v0.z, acc);
        acc = fmaf(fast_tanh(bf2f(u.y >> 16)     + h0.w), v0.w, acc);
        acc = fmaf(fast_tanh(bf2f(u.z & 0xffffu) + h1.x), v1.x, acc);
        acc = fmaf(fast_tanh(bf2f(u.z >> 16)     + h1.y), v1.y, acc);
        acc = fmaf(fast_tanh(bf2f(u.w & 0xffffu) + h1.z), v1.z, acc);
        acc = fmaf(fast_tanh(bf2f(u.w >> 16)     + h1.w), v1.w, acc);
    }
    #pragma unroll
    for (int off = 32; off > 0; off >>= 1) acc += __shfl_down(acc, off);
    if (lane == 0) lam[row] = acc + Vb[0];
}

// ---------------- softmax over p, z = sum_p alpha*f, gate, write inp(bf16) + alphas ----------------
__global__ void __launch_bounds__(256)
attn_z_kernel(const unsigned short* __restrict__ fbf, const float* __restrict__ lam,
              const float* __restrict__ hf, const float* __restrict__ embed_w,
              const int* __restrict__ captions, const int* __restrict__ lens,
              unsigned short* __restrict__ inpbf, float* __restrict__ alphas, int t)
{
    int b = blockIdx.y;
    int tile = blockIdx.x;
    int tid = threadIdx.x;
    if (tile == 4) {   // embedding -> inp[2048:2560]
        int cap = captions[b * TCAP_ + t];
        const float* e = embed_w + (size_t)cap * EMB_;
        int c = tid * 2;
        float2 v = *(const float2*)(e + c);
        *(unsigned int*)(inpbf + (size_t)b * KI_ + E_ + c) =
            (unsigned)f2bf_rne(v.x) | ((unsigned)f2bf_rne(v.y) << 16);
        return;
    }
    __shared__ float sa[256];
    __shared__ float sr[256];
    float x = (tid < P_) ? lam[b * P_ + tid] : -1e30f;
    sr[tid] = x;
    __syncthreads();
    for (int s = 128; s > 0; s >>= 1) {
        if (tid < s) sr[tid] = fmaxf(sr[tid], sr[tid + s]);
        __syncthreads();
    }
    float mx = sr[0];
    __syncthreads();
    float ex = (tid < P_) ? __expf(x - mx) : 0.f;
    sa[tid] = ex;
    sr[tid] = ex;
    __syncthreads();
    for (int s = 128; s > 0; s >>= 1) {
        if (tid < s) sr[tid] += sr[tid + s];
        __syncthreads();
    }
    float inv = 1.0f / sr[0];
    if (tile == 0 && tid < P_) {
        alphas[(size_t)b * TCAP_ * P_ + (size_t)t * P_ + tid] = (lens[b] > t) ? ex * inv : 0.f;
    }
    int e0 = tile * 512 + tid * 2;
    const unsigned short* fp = fbf + (size_t)b * P_ * E_ + e0;
    float a0 = 0.f, a1 = 0.f;
    #pragma unroll 4
    for (int p = 0; p < P_; ++p) {
        unsigned int u = *(const unsigned int*)(const void*)(fp + (size_t)p * E_);
        float ap = sa[p];
        a0 = fmaf(ap, bf2f(u & 0xffffu), a0);
        a1 = fmaf(ap, bf2f(u >> 16), a1);
    }
    a0 *= inv; a1 *= inv;
    float2 gv = *(const float2*)(hf + (size_t)b * E_ + e0);
    float g0 = fast_sig(gv.x), g1 = fast_sig(gv.y);
    *(unsigned int*)(inpbf + (size_t)b * KI_ + e0) =
        (unsigned)f2bf_rne(g0 * a0) | ((unsigned)f2bf_rne(g1 * a1) << 16);
}

// ---------------- fused gi-GEMM + GRU update ----------------
// grid (32, 4): j0 = bx*16 hidden cols, m0 = by*16 batch rows.
// 4 waves split K=2560 into 640-chunks; each wave computes 3 gate tiles (r,z,n);
// LDS reduce; epilogue does the GRU pointwise update and writes h/hbf/Hall.
__global__ void __launch_bounds__(256)
gigru_kernel(const unsigned short* __restrict__ inpbf,
             const unsigned short* __restrict__ wihbf,
             const float* __restrict__ b_ih,
             const float* __restrict__ gh,
             const int* __restrict__ lens,
             float* __restrict__ h, unsigned short* __restrict__ hbf,
             unsigned short* __restrict__ Hall, int t)
{
    __shared__ float red[4][3][16][17];
    int wv = threadIdx.x >> 6, lane = threadIdx.x & 63;
    int mr = lane & 15, quad = lane >> 4;
    int j0 = blockIdx.x * 16;
    int m0 = blockIdx.y * 16;
    int koff = wv * 640;
    const unsigned short* pa = inpbf + (size_t)(m0 + mr) * KI_ + koff + quad * 8;
    const unsigned short* pb0 = wihbf + (size_t)(j0 + mr) * KI_ + koff + quad * 8;
    const unsigned short* pb1 = pb0 + (size_t)512 * KI_;
    const unsigned short* pb2 = pb0 + (size_t)1024 * KI_;
    floatx4 ar = {0.f,0.f,0.f,0.f}, az = {0.f,0.f,0.f,0.f}, an = {0.f,0.f,0.f,0.f};
    #pragma unroll 4
    for (int k0 = 0; k0 < 640; k0 += 32) {
        short8 a = *(const short8*)(const void*)(pa + k0);
        short8 br = *(const short8*)(const void*)(pb0 + k0);
        short8 bz = *(const short8*)(const void*)(pb1 + k0);
        short8 bn = *(const short8*)(const void*)(pb2 + k0);
        ar = __builtin_amdgcn_mfma_f32_16x16x32_bf16(a, br, ar, 0, 0, 0);
        az = __builtin_amdgcn_mfma_f32_16x16x32_bf16(a, bz, az, 0, 0, 0);
        an = __builtin_amdgcn_mfma_f32_16x16x32_bf16(a, bn, an, 0, 0, 0);
    }
    #pragma unroll
    for (int i = 0; i < 4; ++i) {
        red[wv][0][quad * 4 + i][mr] = ar[i];
        red[wv][1][quad * 4 + i][mr] = az[i];
        red[wv][2][quad * 4 + i][mr] = an[i];
    }
    __syncthreads();
    int row = threadIdx.x >> 4, col = threadIdx.x & 15;   // 256 threads = 16x16 patch
    int b = m0 + row, j = j0 + col;
    float ir = red[0][0][row][col] + red[1][0][row][col] + red[2][0][row][col] + red[3][0][row][col] + b_ih[j];
    float iz = red[0][1][row][col] + red[1][1][row][col] + red[2][1][row][col] + red[3][1][row][col] + b_ih[512 + j];
    float in_= red[0][2][row][col] + red[1][2][row][col] + red[2][2][row][col] + red[3][2][row][col] + b_ih[1024 + j];
    float hr = gh[(size_t)b * G3_ + j];
    float hz = gh[(size_t)b * G3_ + 512 + j];
    float hn = gh[(size_t)b * G3_ + 1024 + j];
    float r  = fast_sig(ir + hr);
    float zg = fast_sig(iz + hz);
    float n  = fast_tanh(in_ + r * hn);
    float hp = h[(size_t)b * H_ + j];
    float hv = (1.f - zg) * n + zg * hp;
    float ho = (lens[b] > t) ? hv : hp;
    h[(size_t)b * H_ + j] = ho;
    unsigned short hob = f2bf_rne(ho);
    hbf[(size_t)b * H_ + j] = hob;
    Hall[((size_t)t * B_ + b) * H_ + j] = hob;
}

// ---------------- final big fc1 GEMM over all steps: preds = Hall @ fc1^T ----------------
// Hall: 3136 x 512 bf16 (row = t*64 + b). grid (49, 157), block tile 64m x 64n.
__global__ void __launch_bounds__(256)
fc1all_kernel(const unsigned short* __restrict__ Hall,
              const unsigned short* __restrict__ W,
              const float* __restrict__ bias,
              float* __restrict__ preds, const int* __restrict__ lens)
{
    int wv = threadIdx.x >> 6, lane = threadIdx.x & 63;
    int mr = lane & 15, quad = lane >> 4;
    int t = blockIdx.x;
    int m0 = t * 64 + wv * 16;
    int n0 = blockIdx.y * 64;
    const unsigned short* pa = Hall + (size_t)(m0 + mr) * H_ + quad * 8;
    const unsigned short* pw0 = W + (size_t)min(n0 + mr, V_ - 1) * H_ + quad * 8;
    const unsigned short* pw1 = W + (size_t)min(n0 + 16 + mr, V_ - 1) * H_ + quad * 8;
    const unsigned short* pw2 = W + (size_t)min(n0 + 32 + mr, V_ - 1) * H_ + quad * 8;
    const unsigned short* pw3 = W + (size_t)min(n0 + 48 + mr, V_ - 1) * H_ + quad * 8;
    floatx4 acc[4] = {{0.f,0.f,0.f,0.f},{0.f,0.f,0.f,0.f},{0.f,0.f,0.f,0.f},{0.f,0.f,0.f,0.f}};
    #pragma unroll
    for (int k0 = 0; k0 < H_; k0 += 32) {
        short8 a = *(const short8*)(const void*)(pa + k0);
        short8 b0 = *(const short8*)(const void*)(pw0 + k0);
        short8 b1 = *(const short8*)(const void*)(pw1 + k0);
        short8 b2 = *(const short8*)(const void*)(pw2 + k0);
        short8 b3 = *(const short8*)(const void*)(pw3 + k0);
        acc[0] = __builtin_amdgcn_mfma_f32_16x16x32_bf16(a, b0, acc[0], 0, 0, 0);
        acc[1] = __builtin_amdgcn_mfma_f32_16x16x32_bf16(a, b1, acc[1], 0, 0, 0);
        acc[2] = __builtin_amdgcn_mfma_f32_16x16x32_bf16(a, b2, acc[2], 0, 0, 0);
        acc[3] = __builtin_amdgcn_mfma_f32_16x16x32_bf16(a, b3, acc[3], 0, 0, 0);
    }
    #pragma unroll
    for (int r = 0; r < 4; ++r) {
        int col = n0 + r * 16 + mr;
        if (col >= V_) continue;
        float bs = bias[col];
        #pragma unroll
        for (int i = 0; i < 4; ++i) {
            int row = m0 + quad * 4 + i;      // = t*64 + b_local
            int b = row - t * 64;
            float v = (lens[b] > t) ? (acc[r][i] + bs) : 0.f;
            preds[((size_t)b * TCAP_ + t) * V_ + col] = v;
        }
    }
}

// ---------------- GRU combine placeholder removed (fused into gigru) ----------------

extern "C" void kernel_launch(void* const* d_in, const int* in_sizes, int n_in,
                              void* d_out, int out_size, void* d_ws, size_t ws_size,
                              hipStream_t stream)
{
    const float* features  = (const float*)d_in[0];
    const int*   captions  = (const int*)d_in[1];
    const int*   lengths   = (const int*)d_in[2];
    const float* Wx_w      = (const float*)d_in[3];
    const float* Wx_b      = (const float*)d_in[4];
    const float* Wh_w      = (const float*)d_in[5];
    const float* Wh_b      = (const float*)d_in[6];
    const float* V_w       = (const float*)d_in[7];
    const float* V_b       = (const float*)d_in[8];
    const float* init_h_w  = (const float*)d_in[9];
    const float* init_h_b  = (const float*)d_in[10];
    const float* f_beta_w  = (const float*)d_in[11];
    const float* f_beta_b  = (const float*)d_in[12];
    const float* embed_w   = (const float*)d_in[13];
    const float* gru_w_ih  = (const float*)d_in[14];
    const float* gru_b_ih  = (const float*)d_in[15];
    const float* gru_w_hh  = (const float*)d_in[16];
    const float* gru_b_hh  = (const float*)d_in[17];
    const float* fc1_w     = (const float*)d_in[18];
    const float* fc1_b     = (const float*)d_in[19];

    float* preds  = (float*)d_out;
    float* alphas = preds + (size_t)B_ * TCAP_ * V_;
    float* dec    = alphas + (size_t)B_ * TCAP_ * P_;

    char* w = (char*)d_ws;
    unsigned short* fbf     = (unsigned short*)w; w += (size_t)12544 * 2048 * 2;
    unsigned short* xwx     = (unsigned short*)w; w += (size_t)12544 * 2048 * 2;
    unsigned short* wxbf    = (unsigned short*)w; w += (size_t)2048 * 2048 * 2;
    unsigned short* whbf    = (unsigned short*)w; w += (size_t)2048 * 512 * 2;
    unsigned short* fbbf    = (unsigned short*)w; w += (size_t)2048 * 512 * 2;
    unsigned short* ghhbf   = (unsigned short*)w; w += (size_t)1536 * 512 * 2;
    unsigned short* wihbf   = (unsigned short*)w; w += (size_t)1536 * 2560 * 2;
    unsigned short* fc1bf   = (unsigned short*)w; w += (size_t)10000 * 512 * 2;
    unsigned short* ihwbf   = (unsigned short*)w; w += (size_t)512 * 2048 * 2;
    unsigned short* fmeanbf = (unsigned short*)w; w += (size_t)64 * 2048 * 2;
    unsigned short* hbf     = (unsigned short*)w; w += (size_t)64 * 512 * 2;
    unsigned short* inpbf   = (unsigned short*)w; w += (size_t)64 * KI_ * 2;
    unsigned short* Hall    = (unsigned short*)w; w += (size_t)TMAX_ * 64 * 512 * 2;
    float* h   = (float*)w; w += (size_t)64 * 512 * 4;
    float* hwh = (float*)w; w += (size_t)64 * 2048 * 4;
    float* hf  = (float*)w; w += (size_t)64 * 2048 * 4;
    float* gh  = (float*)w; w += (size_t)64 * 1536 * 4;
    float* lam = (float*)w; w += (size_t)64 * 196 * 4;

    init_out_kernel<<<2500, 256, 0, stream>>>(preds, alphas, dec, lengths);

    f2bf_kernel<<<25088, 256, 0, stream>>>(features, fbf, 12544 * 2048 / 4);
    f2bf_kernel<<<4096, 256, 0, stream>>>(Wx_w, wxbf, 2048 * 2048 / 4);
    f2bf_kernel<<<1024, 256, 0, stream>>>(Wh_w, whbf, 2048 * 512 / 4);
    f2bf_kernel<<<1024, 256, 0, stream>>>(f_beta_w, fbbf, 2048 * 512 / 4);
    f2bf_kernel<<<768, 256, 0, stream>>>(gru_w_hh, ghhbf, 1536 * 512 / 4);
    f2bf_kernel<<<3840, 256, 0, stream>>>(gru_w_ih, wihbf, 1536 * 2560 / 4);
    f2bf_kernel<<<5000, 256, 0, stream>>>(fc1_w, fc1bf, 10000 * 512 / 4);
    f2bf_kernel<<<1024, 256, 0, stream>>>(init_h_w, ihwbf, 512 * 2048 / 4);

    mean_kernel<<<512, 256, 0, stream>>>(features, fmeanbf);
    // h0 = fmean @ init_h_w^T + b  (also writes hbf)
    mfma_gemm64<2048><<<32, 256, 0, stream>>>(fmeanbf, 2048, ihwbf, init_h_b, h, hbf, 512);
    // x_wx (bf16) = features @ Wx^T + b
    mfma_xwx_kernel<<<dim3(196, 32), 256, 0, stream>>>(fbf, wxbf, Wx_b, xwx);

    for (int t = 0; t < TMAX_; ++t) {
        mfma_h3<<<352, 256, 0, stream>>>(hbf, whbf, Wh_b, fbbf, f_beta_b, ghhbf, gru_b_hh,
                                         hwh, hf, gh);
        lam_kernel<<<3136, 256, 0, stream>>>(xwx, hwh, V_w, V_b, lam);
        attn_z_kernel<<<dim3(5, 64), 256, 0, stream>>>(fbf, lam, hf, embed_w, captions,
                                                       lengths, inpbf, alphas, t);
        gigru_kernel<<<dim3(32, 4), 256, 0, stream>>>(inpbf, wihbf, gru_b_ih, gh,
                                                      lengths, h, hbf, Hall, t);
    }
    // preds for all t in one GEMM
    fc1all_kernel<<<dim3(TMAX_, 157), 256, 0, stream>>>(Hall, fc1bf, fc1_b, preds, lengths);
}

// Round 3
// 4015.918 us; speedup vs baseline: 1.2133x; 1.1020x over previous
//
#include <hip/hip_runtime.h>
#include <cstddef>

#define B_    64
#define P_    196
#define E_    2048
#define H_    512
#define EMB_  512
#define V_    10000
#define TCAP_ 50
#define TMAX_ 49
#define KI_   2560   // E_ + EMB_
#define G3_   1536   // 3*H_

typedef __attribute__((ext_vector_type(8))) short short8;
typedef __attribute__((ext_vector_type(4))) float floatx4;
typedef unsigned int u32;
typedef const __attribute__((address_space(1))) u32* gptr_t;
typedef __attribute__((address_space(3))) u32* lptr_t;

__device__ __forceinline__ unsigned short f2bf_rne(float f) {
    unsigned int x = __float_as_uint(f);
    unsigned int r = (x + 0x7fffu + ((x >> 16) & 1u)) >> 16;
    return (unsigned short)r;
}
__device__ __forceinline__ float bf2f(unsigned int u16) {
    return __uint_as_float(u16 << 16);
}
__device__ __forceinline__ float fast_tanh(float x) {
    float a = fabsf(x);
    float e = __expf(2.0f * a);
    float r = 1.0f - 2.0f / (e + 1.0f);
    return (x < 0.0f) ? -r : r;
}
__device__ __forceinline__ float fast_sig(float x) {
    return 1.0f / (1.0f + __expf(-x));
}

// ---------------- output init: zero t=49 slices, write dec ----------------
__global__ void init_out_kernel(float* __restrict__ preds, float* __restrict__ alphas,
                                float* __restrict__ dec, const int* __restrict__ lens)
{
    int i = blockIdx.x * 256 + threadIdx.x;
    if (i < B_ * V_) {
        int b = i / V_, v = i - b * V_;
        preds[((size_t)b * TCAP_ + TMAX_) * V_ + v] = 0.f;
    }
    if (i < B_ * P_) {
        int b = i / P_, p = i - b * P_;
        alphas[((size_t)b * TCAP_ + TMAX_) * P_ + p] = 0.f;
    }
    if (i < B_) dec[i] = (float)(lens[i] - 1);
}

// ---------------- f32 -> bf16 cast (8 elems/thread) ----------------
__global__ void f2bf_kernel(const float* __restrict__ src, unsigned short* __restrict__ dst, int n8)
{
    int i = blockIdx.x * 256 + threadIdx.x;
    if (i >= n8) return;
    float4 a = ((const float4*)src)[2 * i];
    float4 b = ((const float4*)src)[2 * i + 1];
    uint4 o;
    o.x = (unsigned)f2bf_rne(a.x) | ((unsigned)f2bf_rne(a.y) << 16);
    o.y = (unsigned)f2bf_rne(a.z) | ((unsigned)f2bf_rne(a.w) << 16);
    o.z = (unsigned)f2bf_rne(b.x) | ((unsigned)f2bf_rne(b.y) << 16);
    o.w = (unsigned)f2bf_rne(b.z) | ((unsigned)f2bf_rne(b.w) << 16);
    ((uint4*)dst)[i] = o;
}

// ---------------- mean over P, output bf16 (64 x 2048) ----------------
__global__ void mean_kernel(const float* __restrict__ f, unsigned short* __restrict__ out)
{
    int i = blockIdx.x * 256 + threadIdx.x;
    int b = i >> 11, e = i & 2047;
    const float* p = f + (size_t)b * P_ * E_ + e;
    float s = 0.f;
    #pragma unroll 4
    for (int k = 0; k < P_; ++k) s += p[(size_t)k * E_];
    out[i] = f2bf_rne(s * (1.0f / (float)P_));
}

// ---------------- xwx GEMM, m97-style LDS-staged: 128x128 tile, BK=64 ----------------
// grid (16, 98): x = n-tile, y = m-tile. block = 256 threads = 4 waves (2x2 of 64x64).
__global__ void __launch_bounds__(256)
mfma_xwx_kernel(const unsigned short* __restrict__ A,   // [12544][2048]
                const unsigned short* __restrict__ W,   // [2048][2048]
                const float* __restrict__ bias,
                unsigned short* __restrict__ C)         // [12544][2048] bf16
{
    __shared__ unsigned short As[128 * 64];   // 16 KB
    __shared__ unsigned short Bs[128 * 64];   // 16 KB
    int wv = threadIdx.x >> 6, lane = threadIdx.x & 63;
    int mr = lane & 15, quad = lane >> 4;
    int m0 = blockIdx.y * 128;
    int n0 = blockIdx.x * 128;
    int wm = (wv & 1) * 64, wn = (wv >> 1) * 64;
    int srow = wv * 32;            // staging: this wave covers 32 rows of each tile
    int lrow = lane >> 3;          // 0..7
    int lcol = (lane & 7) * 8;     // shorts (16 B)
    floatx4 acc[4][4] = {};
    for (int k0 = 0; k0 < E_; k0 += 64) {
        __syncthreads();
        #pragma unroll
        for (int i = 0; i < 4; ++i) {
            int r = srow + i * 8;
            __builtin_amdgcn_global_load_lds(
                (gptr_t)(A + (size_t)(m0 + r + lrow) * E_ + k0 + lcol),
                (lptr_t)(As + r * 64), 16, 0, 0);
            __builtin_amdgcn_global_load_lds(
                (gptr_t)(W + (size_t)(n0 + r + lrow) * E_ + k0 + lcol),
                (lptr_t)(Bs + r * 64), 16, 0, 0);
        }
        __syncthreads();
        #pragma unroll
        for (int kk = 0; kk < 64; kk += 32) {
            short8 af[4], bf[4];
            #pragma unroll
            for (int i = 0; i < 4; ++i)
                af[i] = *(const short8*)(As + (wm + i * 16 + mr) * 64 + kk + quad * 8);
            #pragma unroll
            for (int j = 0; j < 4; ++j)
                bf[j] = *(const short8*)(Bs + (wn + j * 16 + mr) * 64 + kk + quad * 8);
            #pragma unroll
            for (int i = 0; i < 4; ++i)
                #pragma unroll
                for (int j = 0; j < 4; ++j)
                    acc[i][j] = __builtin_amdgcn_mfma_f32_16x16x32_bf16(af[i], bf[j], acc[i][j], 0, 0, 0);
        }
    }
    #pragma unroll
    for (int j = 0; j < 4; ++j) {
        int col = n0 + wn + j * 16 + mr;
        float bs = bias[col];
        #pragma unroll
        for (int i = 0; i < 4; ++i) {
            int row = m0 + wm + i * 16 + quad * 4;
            #pragma unroll
            for (int ii = 0; ii < 4; ++ii)
                C[(size_t)(row + ii) * E_ + col] = f2bf_rne(acc[i][j][ii] + bs);
        }
    }
}

// ---------------- skinny MFMA GEMM (used once for h0) ----------------
template<int KC>
__global__ void __launch_bounds__(256)
mfma_gemm64(const unsigned short* __restrict__ A, int ld,
            const unsigned short* __restrict__ W,
            const float* __restrict__ bias,
            float* __restrict__ C, unsigned short* __restrict__ Cbf, int ldc)
{
    int wv = threadIdx.x >> 6, lane = threadIdx.x & 63;
    int mr = lane & 15, quad = lane >> 4;
    int m0 = wv * 16;
    int n0 = blockIdx.x * 16;
    const unsigned short* pa = A + (size_t)(m0 + mr) * ld + quad * 8;
    const unsigned short* pb = W + (size_t)(n0 + mr) * ld + quad * 8;
    floatx4 acc = {0.f, 0.f, 0.f, 0.f};
    #pragma unroll 16
    for (int k0 = 0; k0 < KC; k0 += 32) {
        short8 a = *(const short8*)(const void*)(pa + k0);
        short8 b = *(const short8*)(const void*)(pb + k0);
        acc = __builtin_amdgcn_mfma_f32_16x16x32_bf16(a, b, acc, 0, 0, 0);
    }
    int col = n0 + mr;
    float bs = bias ? bias[col] : 0.f;
    #pragma unroll
    for (int i = 0; i < 4; ++i) {
        int row = m0 + quad * 4 + i;
        float v = acc[i] + bs;
        C[(size_t)row * ldc + col] = v;
        if (Cbf) Cbf[(size_t)row * ldc + col] = f2bf_rne(v);
    }
}

// ---------------- fused h-projections: hwh (2048), hf (2048), gh (1536); K=512 ----------------
__global__ void __launch_bounds__(256)
mfma_h3(const unsigned short* __restrict__ hbf,
        const unsigned short* __restrict__ whbf, const float* __restrict__ Wh_b,
        const unsigned short* __restrict__ fbbf, const float* __restrict__ fb_b,
        const unsigned short* __restrict__ ghhbf, const float* __restrict__ ghh_b,
        float* __restrict__ hwh, float* __restrict__ hf, float* __restrict__ gh)
{
    int bt = blockIdx.x;   // 0..351
    const unsigned short* W; const float* bias; float* C; int n0; int ldc;
    if (bt < 128)      { W = whbf;  bias = Wh_b;  C = hwh; n0 = bt * 16;         ldc = E_; }
    else if (bt < 256) { W = fbbf;  bias = fb_b;  C = hf;  n0 = (bt - 128) * 16; ldc = E_; }
    else               { W = ghhbf; bias = ghh_b; C = gh;  n0 = (bt - 256) * 16; ldc = G3_; }
    int wv = threadIdx.x >> 6, lane = threadIdx.x & 63;
    int mr = lane & 15, quad = lane >> 4;
    int m0 = wv * 16;
    const unsigned short* pa = hbf + (size_t)(m0 + mr) * H_ + quad * 8;
    const unsigned short* pb = W + (size_t)(n0 + mr) * H_ + quad * 8;
    floatx4 acc0 = {0.f, 0.f, 0.f, 0.f};
    floatx4 acc1 = {0.f, 0.f, 0.f, 0.f};
    #pragma unroll
    for (int k0 = 0; k0 < 256; k0 += 32) {
        short8 a0 = *(const short8*)(const void*)(pa + k0);
        short8 b0 = *(const short8*)(const void*)(pb + k0);
        acc0 = __builtin_amdgcn_mfma_f32_16x16x32_bf16(a0, b0, acc0, 0, 0, 0);
        short8 a1 = *(const short8*)(const void*)(pa + k0 + 256);
        short8 b1 = *(const short8*)(const void*)(pb + k0 + 256);
        acc1 = __builtin_amdgcn_mfma_f32_16x16x32_bf16(a1, b1, acc1, 0, 0, 0);
    }
    floatx4 acc = acc0 + acc1;
    int col = n0 + mr;
    float bs = bias[col];
    #pragma unroll
    for (int i = 0; i < 4; ++i) {
        int row = m0 + quad * 4 + i;
        C[(size_t)row * ldc + col] = acc[i] + bs;
    }
}

// ---------------- lam: block = (16 p-rows, one b); hwh[b]+Vw staged in LDS ----------------
// grid (13, 64)
__global__ void __launch_bounds__(256)
lam_kernel(const unsigned short* __restrict__ xwx, const float* __restrict__ hwh,
           const float* __restrict__ Vw, const float* __restrict__ Vb,
           float* __restrict__ lam)
{
    __shared__ float sh[E_];   // 8 KB
    __shared__ float sv[E_];   // 8 KB
    int b = blockIdx.y;
    int p0 = blockIdx.x * 16;
    int tid = threadIdx.x;
    {
        const float4* hs = (const float4*)(hwh + (size_t)b * E_);
        const float4* vs = (const float4*)Vw;
        ((float4*)sh)[tid]       = hs[tid];
        ((float4*)sh)[tid + 256] = hs[tid + 256];
        ((float4*)sv)[tid]       = vs[tid];
        ((float4*)sv)[tid + 256] = vs[tid + 256];
    }
    __syncthreads();
    int wv = tid >> 6, lane = tid & 63;
    #pragma unroll
    for (int r = 0; r < 4; ++r) {
        int p = p0 + wv * 4 + r;
        if (p < P_) {
            const unsigned short* px = xwx + ((size_t)b * P_ + p) * E_;
            float acc = 0.f;
            #pragma unroll
            for (int it = 0; it < 4; ++it) {
                int e = it * 512 + lane * 8;
                uint4 u = *(const uint4*)(const void*)(px + e);
                float4 h0 = *(const float4*)(sh + e);
                float4 h1 = *(const float4*)(sh + e + 4);
                float4 v0 = *(const float4*)(sv + e);
                float4 v1 = *(const float4*)(sv + e + 4);
                acc = fmaf(fast_tanh(bf2f(u.x & 0xffffu) + h0.x), v0.x, acc);
                acc = fmaf(fast_tanh(bf2f(u.x >> 16)     + h0.y), v0.y, acc);
                acc = fmaf(fast_tanh(bf2f(u.y & 0xffffu) + h0.z), v0.z, acc);
                acc = fmaf(fast_tanh(bf2f(u.y >> 16)     + h0.w), v0.w, acc);
                acc = fmaf(fast_tanh(bf2f(u.z & 0xffffu) + h1.x), v1.x, acc);
                acc = fmaf(fast_tanh(bf2f(u.z >> 16)     + h1.y), v1.y, acc);
                acc = fmaf(fast_tanh(bf2f(u.w & 0xffffu) + h1.z), v1.z, acc);
                acc = fmaf(fast_tanh(bf2f(u.w >> 16)     + h1.w), v1.w, acc);
            }
            #pragma unroll
            for (int off = 32; off > 0; off >>= 1) acc += __shfl_down(acc, off);
            if (lane == 0) lam[b * P_ + p] = acc + Vb[0];
        }
    }
}

// ---------------- softmax over p, z = sum_p alpha*f, gate, write inp(bf16) + alphas ----------------
__global__ void __launch_bounds__(256)
attn_z_kernel(const unsigned short* __restrict__ fbf, const float* __restrict__ lam,
              const float* __restrict__ hf, const float* __restrict__ embed_w,
              const int* __restrict__ captions, const int* __restrict__ lens,
              unsigned short* __restrict__ inpbf, float* __restrict__ alphas, int t)
{
    int b = blockIdx.y;
    int tile = blockIdx.x;
    int tid = threadIdx.x;
    if (tile == 4) {   // embedding -> inp[2048:2560]
        int cap = captions[b * TCAP_ + t];
        const float* e = embed_w + (size_t)cap * EMB_;
        int c = tid * 2;
        float2 v = *(const float2*)(e + c);
        *(unsigned int*)(inpbf + (size_t)b * KI_ + E_ + c) =
            (unsigned)f2bf_rne(v.x) | ((unsigned)f2bf_rne(v.y) << 16);
        return;
    }
    __shared__ float sa[256];
    __shared__ float sr[256];
    float x = (tid < P_) ? lam[b * P_ + tid] : -1e30f;
    sr[tid] = x;
    __syncthreads();
    for (int s = 128; s > 0; s >>= 1) {
        if (tid < s) sr[tid] = fmaxf(sr[tid], sr[tid + s]);
        __syncthreads();
    }
    float mx = sr[0];
    __syncthreads();
    float ex = (tid < P_) ? __expf(x - mx) : 0.f;
    sa[tid] = ex;
    sr[tid] = ex;
    __syncthreads();
    for (int s = 128; s > 0; s >>= 1) {
        if (tid < s) sr[tid] += sr[tid + s];
        __syncthreads();
    }
    float inv = 1.0f / sr[0];
    if (tile == 0 && tid < P_) {
        alphas[(size_t)b * TCAP_ * P_ + (size_t)t * P_ + tid] = (lens[b] > t) ? ex * inv : 0.f;
    }
    int e0 = tile * 512 + tid * 2;
    const unsigned short* fp = fbf + (size_t)b * P_ * E_ + e0;
    float a0 = 0.f, a1 = 0.f;
    #pragma unroll 4
    for (int p = 0; p < P_; ++p) {
        unsigned int u = *(const unsigned int*)(const void*)(fp + (size_t)p * E_);
        float ap = sa[p];
        a0 = fmaf(ap, bf2f(u & 0xffffu), a0);
        a1 = fmaf(ap, bf2f(u >> 16), a1);
    }
    a0 *= inv; a1 *= inv;
    float2 gv = *(const float2*)(hf + (size_t)b * E_ + e0);
    float g0 = fast_sig(gv.x), g1 = fast_sig(gv.y);
    *(unsigned int*)(inpbf + (size_t)b * KI_ + e0) =
        (unsigned)f2bf_rne(g0 * a0) | ((unsigned)f2bf_rne(g1 * a1) << 16);
}

// ---------------- fused gi-GEMM + GRU update ----------------
__global__ void __launch_bounds__(256)
gigru_kernel(const unsigned short* __restrict__ inpbf,
             const unsigned short* __restrict__ wihbf,
             const float* __restrict__ b_ih,
             const float* __restrict__ gh,
             const int* __restrict__ lens,
             float* __restrict__ h, unsigned short* __restrict__ hbf,
             unsigned short* __restrict__ Hall, int t)
{
    __shared__ float red[4][3][16][17];
    int wv = threadIdx.x >> 6, lane = threadIdx.x & 63;
    int mr = lane & 15, quad = lane >> 4;
    int j0 = blockIdx.x * 16;
    int m0 = blockIdx.y * 16;
    int koff = wv * 640;
    const unsigned short* pa = inpbf + (size_t)(m0 + mr) * KI_ + koff + quad * 8;
    const unsigned short* pb0 = wihbf + (size_t)(j0 + mr) * KI_ + koff + quad * 8;
    const unsigned short* pb1 = pb0 + (size_t)512 * KI_;
    const unsigned short* pb2 = pb0 + (size_t)1024 * KI_;
    floatx4 ar = {0.f,0.f,0.f,0.f}, az = {0.f,0.f,0.f,0.f}, an = {0.f,0.f,0.f,0.f};
    #pragma unroll 4
    for (int k0 = 0; k0 < 640; k0 += 32) {
        short8 a = *(const short8*)(const void*)(pa + k0);
        short8 br = *(const short8*)(const void*)(pb0 + k0);
        short8 bz = *(const short8*)(const void*)(pb1 + k0);
        short8 bn = *(const short8*)(const void*)(pb2 + k0);
        ar = __builtin_amdgcn_mfma_f32_16x16x32_bf16(a, br, ar, 0, 0, 0);
        az = __builtin_amdgcn_mfma_f32_16x16x32_bf16(a, bz, az, 0, 0, 0);
        an = __builtin_amdgcn_mfma_f32_16x16x32_bf16(a, bn, an, 0, 0, 0);
    }
    #pragma unroll
    for (int i = 0; i < 4; ++i) {
        red[wv][0][quad * 4 + i][mr] = ar[i];
        red[wv][1][quad * 4 + i][mr] = az[i];
        red[wv][2][quad * 4 + i][mr] = an[i];
    }
    __syncthreads();
    int row = threadIdx.x >> 4, col = threadIdx.x & 15;
    int b = m0 + row, j = j0 + col;
    float ir = red[0][0][row][col] + red[1][0][row][col] + red[2][0][row][col] + red[3][0][row][col] + b_ih[j];
    float iz = red[0][1][row][col] + red[1][1][row][col] + red[2][1][row][col] + red[3][1][row][col] + b_ih[512 + j];
    float in_= red[0][2][row][col] + red[1][2][row][col] + red[2][2][row][col] + red[3][2][row][col] + b_ih[1024 + j];
    float hr = gh[(size_t)b * G3_ + j];
    float hz = gh[(size_t)b * G3_ + 512 + j];
    float hn = gh[(size_t)b * G3_ + 1024 + j];
    float r  = fast_sig(ir + hr);
    float zg = fast_sig(iz + hz);
    float n  = fast_tanh(in_ + r * hn);
    float hp = h[(size_t)b * H_ + j];
    float hv = (1.f - zg) * n + zg * hp;
    float ho = (lens[b] > t) ? hv : hp;
    h[(size_t)b * H_ + j] = ho;
    unsigned short hob = f2bf_rne(ho);
    hbf[(size_t)b * H_ + j] = hob;
    Hall[((size_t)t * B_ + b) * H_ + j] = hob;
}

// ---------------- final big fc1 GEMM over all steps: preds = Hall @ fc1^T ----------------
__global__ void __launch_bounds__(256)
fc1all_kernel(const unsigned short* __restrict__ Hall,
              const unsigned short* __restrict__ W,
              const float* __restrict__ bias,
              float* __restrict__ preds, const int* __restrict__ lens)
{
    int wv = threadIdx.x >> 6, lane = threadIdx.x & 63;
    int mr = lane & 15, quad = lane >> 4;
    int t = blockIdx.x;
    int m0 = t * 64 + wv * 16;
    int n0 = blockIdx.y * 64;
    const unsigned short* pa = Hall + (size_t)(m0 + mr) * H_ + quad * 8;
    const unsigned short* pw0 = W + (size_t)min(n0 + mr, V_ - 1) * H_ + quad * 8;
    const unsigned short* pw1 = W + (size_t)min(n0 + 16 + mr, V_ - 1) * H_ + quad * 8;
    const unsigned short* pw2 = W + (size_t)min(n0 + 32 + mr, V_ - 1) * H_ + quad * 8;
    const unsigned short* pw3 = W + (size_t)min(n0 + 48 + mr, V_ - 1) * H_ + quad * 8;
    floatx4 acc[4] = {{0.f,0.f,0.f,0.f},{0.f,0.f,0.f,0.f},{0.f,0.f,0.f,0.f},{0.f,0.f,0.f,0.f}};
    #pragma unroll
    for (int k0 = 0; k0 < H_; k0 += 32) {
        short8 a = *(const short8*)(const void*)(pa + k0);
        short8 b0 = *(const short8*)(const void*)(pw0 + k0);
        short8 b1 = *(const short8*)(const void*)(pw1 + k0);
        short8 b2 = *(const short8*)(const void*)(pw2 + k0);
        short8 b3 = *(const short8*)(const void*)(pw3 + k0);
        acc[0] = __builtin_amdgcn_mfma_f32_16x16x32_bf16(a, b0, acc[0], 0, 0, 0);
        acc[1] = __builtin_amdgcn_mfma_f32_16x16x32_bf16(a, b1, acc[1], 0, 0, 0);
        acc[2] = __builtin_amdgcn_mfma_f32_16x16x32_bf16(a, b2, acc[2], 0, 0, 0);
        acc[3] = __builtin_amdgcn_mfma_f32_16x16x32_bf16(a, b3, acc[3], 0, 0, 0);
    }
    #pragma unroll
    for (int r = 0; r < 4; ++r) {
        int col = n0 + r * 16 + mr;
        if (col >= V_) continue;
        float bs = bias[col];
        #pragma unroll
        for (int i = 0; i < 4; ++i) {
            int row = m0 + quad * 4 + i;
            int b = row - t * 64;
            float v = (lens[b] > t) ? (acc[r][i] + bs) : 0.f;
            preds[((size_t)b * TCAP_ + t) * V_ + col] = v;
        }
    }
}

extern "C" void kernel_launch(void* const* d_in, const int* in_sizes, int n_in,
                              void* d_out, int out_size, void* d_ws, size_t ws_size,
                              hipStream_t stream)
{
    const float* features  = (const float*)d_in[0];
    const int*   captions  = (const int*)d_in[1];
    const int*   lengths   = (const int*)d_in[2];
    const float* Wx_w      = (const float*)d_in[3];
    const float* Wx_b      = (const float*)d_in[4];
    const float* Wh_w      = (const float*)d_in[5];
    const float* Wh_b      = (const float*)d_in[6];
    const float* V_w       = (const float*)d_in[7];
    const float* V_b       = (const float*)d_in[8];
    const float* init_h_w  = (const float*)d_in[9];
    const float* init_h_b  = (const float*)d_in[10];
    const float* f_beta_w  = (const float*)d_in[11];
    const float* f_beta_b  = (const float*)d_in[12];
    const float* embed_w   = (const float*)d_in[13];
    const float* gru_w_ih  = (const float*)d_in[14];
    const float* gru_b_ih  = (const float*)d_in[15];
    const float* gru_w_hh  = (const float*)d_in[16];
    const float* gru_b_hh  = (const float*)d_in[17];
    const float* fc1_w     = (const float*)d_in[18];
    const float* fc1_b     = (const float*)d_in[19];

    float* preds  = (float*)d_out;
    float* alphas = preds + (size_t)B_ * TCAP_ * V_;
    float* dec    = alphas + (size_t)B_ * TCAP_ * P_;

    char* w = (char*)d_ws;
    unsigned short* fbf     = (unsigned short*)w; w += (size_t)12544 * 2048 * 2;
    unsigned short* xwx     = (unsigned short*)w; w += (size_t)12544 * 2048 * 2;
    unsigned short* wxbf    = (unsigned short*)w; w += (size_t)2048 * 2048 * 2;
    unsigned short* whbf    = (unsigned short*)w; w += (size_t)2048 * 512 * 2;
    unsigned short* fbbf    = (unsigned short*)w; w += (size_t)2048 * 512 * 2;
    unsigned short* ghhbf   = (unsigned short*)w; w += (size_t)1536 * 512 * 2;
    unsigned short* wihbf   = (unsigned short*)w; w += (size_t)1536 * 2560 * 2;
    unsigned short* fc1bf   = (unsigned short*)w; w += (size_t)10000 * 512 * 2;
    unsigned short* ihwbf   = (unsigned short*)w; w += (size_t)512 * 2048 * 2;
    unsigned short* fmeanbf = (unsigned short*)w; w += (size_t)64 * 2048 * 2;
    unsigned short* hbf     = (unsigned short*)w; w += (size_t)64 * 512 * 2;
    unsigned short* inpbf   = (unsigned short*)w; w += (size_t)64 * KI_ * 2;
    unsigned short* Hall    = (unsigned short*)w; w += (size_t)TMAX_ * 64 * 512 * 2;
    float* h   = (float*)w; w += (size_t)64 * 512 * 4;
    float* hwh = (float*)w; w += (size_t)64 * 2048 * 4;
    float* hf  = (float*)w; w += (size_t)64 * 2048 * 4;
    float* gh  = (float*)w; w += (size_t)64 * 1536 * 4;
    float* lam = (float*)w; w += (size_t)64 * 196 * 4;

    init_out_kernel<<<2500, 256, 0, stream>>>(preds, alphas, dec, lengths);

    f2bf_kernel<<<12544, 256, 0, stream>>>(features, fbf, 12544 * 2048 / 8);
    f2bf_kernel<<<2048, 256, 0, stream>>>(Wx_w, wxbf, 2048 * 2048 / 8);
    f2bf_kernel<<<512, 256, 0, stream>>>(Wh_w, whbf, 2048 * 512 / 8);
    f2bf_kernel<<<512, 256, 0, stream>>>(f_beta_w, fbbf, 2048 * 512 / 8);
    f2bf_kernel<<<384, 256, 0, stream>>>(gru_w_hh, ghhbf, 1536 * 512 / 8);
    f2bf_kernel<<<1920, 256, 0, stream>>>(gru_w_ih, wihbf, 1536 * 2560 / 8);
    f2bf_kernel<<<2500, 256, 0, stream>>>(fc1_w, fc1bf, 10000 * 512 / 8);
    f2bf_kernel<<<512, 256, 0, stream>>>(init_h_w, ihwbf, 512 * 2048 / 8);

    mean_kernel<<<512, 256, 0, stream>>>(features, fmeanbf);
    mfma_gemm64<2048><<<32, 256, 0, stream>>>(fmeanbf, 2048, ihwbf, init_h_b, h, hbf, 512);
    // x_wx (bf16) = features @ Wx^T + b   — LDS-staged 128x128 tiles
    mfma_xwx_kernel<<<dim3(16, 98), 256, 0, stream>>>(fbf, wxbf, Wx_b, xwx);

    for (int t = 0; t < TMAX_; ++t) {
        mfma_h3<<<352, 256, 0, stream>>>(hbf, whbf, Wh_b, fbbf, f_beta_b, ghhbf, gru_b_hh,
                                         hwh, hf, gh);
        lam_kernel<<<dim3(13, 64), 256, 0, stream>>>(xwx, hwh, V_w, V_b, lam);
        attn_z_kernel<<<dim3(5, 64), 256, 0, stream>>>(fbf, lam, hf, embed_w, captions,
                                                       lengths, inpbf, alphas, t);
        gigru_kernel<<<dim3(32, 4), 256, 0, stream>>>(inpbf, wihbf, gru_b_ih, gh,
                                                      lengths, h, hbf, Hall, t);
    }
    fc1all_kernel<<<dim3(TMAX_, 157), 256, 0, stream>>>(Hall, fc1bf, fc1_b, preds, lengths);
}

// Round 4
// 3327.581 us; speedup vs baseline: 1.4643x; 1.2069x over previous
//
#include <hip/hip_runtime.h>
#include <cstddef>

#define B_    64
#define P_    196
#define E_    2048
#define H_    512
#define EMB_  512
#define V_    10000
#define TCAP_ 50
#define TMAX_ 49
#define KI_   2560   // E_ + EMB_
#define G3_   1536   // 3*H_

typedef __attribute__((ext_vector_type(8))) short short8;
typedef __attribute__((ext_vector_type(4))) float floatx4;
typedef unsigned int u32;
typedef const __attribute__((address_space(1))) u32* gptr_t;
typedef __attribute__((address_space(3))) u32* lptr_t;

__device__ __forceinline__ unsigned short f2bf_rne(float f) {
    unsigned int x = __float_as_uint(f);
    unsigned int r = (x + 0x7fffu + ((x >> 16) & 1u)) >> 16;
    return (unsigned short)r;
}
__device__ __forceinline__ float bf2f(unsigned int u16) {
    return __uint_as_float(u16 << 16);
}
__device__ __forceinline__ float fast_tanh(float x) {
    float a = fabsf(x);
    float e = __expf(2.0f * a);
    float r = 1.0f - 2.0f / (e + 1.0f);
    return (x < 0.0f) ? -r : r;
}
__device__ __forceinline__ float fast_sig(float x) {
    return 1.0f / (1.0f + __expf(-x));
}

// ---------------- output init: zero t=49 slices, write dec ----------------
__global__ void init_out_kernel(float* __restrict__ preds, float* __restrict__ alphas,
                                float* __restrict__ dec, const int* __restrict__ lens)
{
    int i = blockIdx.x * 256 + threadIdx.x;
    if (i < B_ * V_) {
        int b = i / V_, v = i - b * V_;
        preds[((size_t)b * TCAP_ + TMAX_) * V_ + v] = 0.f;
    }
    if (i < B_ * P_) {
        int b = i / P_, p = i - b * P_;
        alphas[((size_t)b * TCAP_ + TMAX_) * P_ + p] = 0.f;
    }
    if (i < B_) dec[i] = (float)(lens[i] - 1);
}

// ---------------- f32 -> bf16 cast (8 elems/thread) ----------------
__global__ void f2bf_kernel(const float* __restrict__ src, unsigned short* __restrict__ dst, int n8)
{
    int i = blockIdx.x * 256 + threadIdx.x;
    if (i >= n8) return;
    float4 a = ((const float4*)src)[2 * i];
    float4 b = ((const float4*)src)[2 * i + 1];
    uint4 o;
    o.x = (unsigned)f2bf_rne(a.x) | ((unsigned)f2bf_rne(a.y) << 16);
    o.y = (unsigned)f2bf_rne(a.z) | ((unsigned)f2bf_rne(a.w) << 16);
    o.z = (unsigned)f2bf_rne(b.x) | ((unsigned)f2bf_rne(b.y) << 16);
    o.w = (unsigned)f2bf_rne(b.z) | ((unsigned)f2bf_rne(b.w) << 16);
    ((uint4*)dst)[i] = o;
}

// ---------------- mean over P, output bf16 (64 x 2048) ----------------
__global__ void mean_kernel(const float* __restrict__ f, unsigned short* __restrict__ out)
{
    int i = blockIdx.x * 256 + threadIdx.x;
    int b = i >> 11, e = i & 2047;
    const float* p = f + (size_t)b * P_ * E_ + e;
    float s = 0.f;
    #pragma unroll 4
    for (int k = 0; k < P_; ++k) s += p[(size_t)k * E_];
    out[i] = f2bf_rne(s * (1.0f / (float)P_));
}

// ---------------- xwx GEMM, LDS-staged: 128x128 tile, BK=64 ----------------
__global__ void __launch_bounds__(256)
mfma_xwx_kernel(const unsigned short* __restrict__ A,   // [12544][2048]
                const unsigned short* __restrict__ W,   // [2048][2048]
                const float* __restrict__ bias,
                unsigned short* __restrict__ C)         // [12544][2048] bf16
{
    __shared__ unsigned short As[128 * 64];
    __shared__ unsigned short Bs[128 * 64];
    int wv = threadIdx.x >> 6, lane = threadIdx.x & 63;
    int mr = lane & 15, quad = lane >> 4;
    int m0 = blockIdx.y * 128;
    int n0 = blockIdx.x * 128;
    int wm = (wv & 1) * 64, wn = (wv >> 1) * 64;
    int srow = wv * 32;
    int lrow = lane >> 3;
    int lcol = (lane & 7) * 8;
    floatx4 acc[4][4] = {};
    for (int k0 = 0; k0 < E_; k0 += 64) {
        __syncthreads();
        #pragma unroll
        for (int i = 0; i < 4; ++i) {
            int r = srow + i * 8;
            __builtin_amdgcn_global_load_lds(
                (gptr_t)(A + (size_t)(m0 + r + lrow) * E_ + k0 + lcol),
                (lptr_t)(As + r * 64), 16, 0, 0);
            __builtin_amdgcn_global_load_lds(
                (gptr_t)(W + (size_t)(n0 + r + lrow) * E_ + k0 + lcol),
                (lptr_t)(Bs + r * 64), 16, 0, 0);
        }
        __syncthreads();
        #pragma unroll
        for (int kk = 0; kk < 64; kk += 32) {
            short8 af[4], bf[4];
            #pragma unroll
            for (int i = 0; i < 4; ++i)
                af[i] = *(const short8*)(As + (wm + i * 16 + mr) * 64 + kk + quad * 8);
            #pragma unroll
            for (int j = 0; j < 4; ++j)
                bf[j] = *(const short8*)(Bs + (wn + j * 16 + mr) * 64 + kk + quad * 8);
            #pragma unroll
            for (int i = 0; i < 4; ++i)
                #pragma unroll
                for (int j = 0; j < 4; ++j)
                    acc[i][j] = __builtin_amdgcn_mfma_f32_16x16x32_bf16(af[i], bf[j], acc[i][j], 0, 0, 0);
        }
    }
    #pragma unroll
    for (int j = 0; j < 4; ++j) {
        int col = n0 + wn + j * 16 + mr;
        float bs = bias[col];
        #pragma unroll
        for (int i = 0; i < 4; ++i) {
            int row = m0 + wm + i * 16 + quad * 4;
            #pragma unroll
            for (int ii = 0; ii < 4; ++ii)
                C[(size_t)(row + ii) * E_ + col] = f2bf_rne(acc[i][j][ii] + bs);
        }
    }
}

// ---------------- fc1 over all steps, LDS-staged: 128x128 tile, K=512 ----------------
// grid (79, 25). Hall row = t*64+b; preds[(b*50+t)*V + col], masked.
__global__ void __launch_bounds__(256)
fc1tile_kernel(const unsigned short* __restrict__ Hall,  // [3136][512] (+OOB slack)
               const unsigned short* __restrict__ W,     // [10000][512] (+OOB slack)
               const float* __restrict__ bias,
               float* __restrict__ preds, const int* __restrict__ lens)
{
    __shared__ unsigned short As[128 * 64];
    __shared__ unsigned short Bs[128 * 64];
    int wv = threadIdx.x >> 6, lane = threadIdx.x & 63;
    int mr = lane & 15, quad = lane >> 4;
    int m0 = blockIdx.y * 128;
    int n0 = blockIdx.x * 128;
    int wm = (wv & 1) * 64, wn = (wv >> 1) * 64;
    int srow = wv * 32;
    int lrow = lane >> 3;
    int lcol = (lane & 7) * 8;
    floatx4 acc[4][4] = {};
    for (int k0 = 0; k0 < H_; k0 += 64) {
        __syncthreads();
        #pragma unroll
        for (int i = 0; i < 4; ++i) {
            int r = srow + i * 8;
            __builtin_amdgcn_global_load_lds(
                (gptr_t)(Hall + (size_t)(m0 + r + lrow) * H_ + k0 + lcol),
                (lptr_t)(As + r * 64), 16, 0, 0);
            __builtin_amdgcn_global_load_lds(
                (gptr_t)(W + (size_t)(n0 + r + lrow) * H_ + k0 + lcol),
                (lptr_t)(Bs + r * 64), 16, 0, 0);
        }
        __syncthreads();
        #pragma unroll
        for (int kk = 0; kk < 64; kk += 32) {
            short8 af[4], bf[4];
            #pragma unroll
            for (int i = 0; i < 4; ++i)
                af[i] = *(const short8*)(As + (wm + i * 16 + mr) * 64 + kk + quad * 8);
            #pragma unroll
            for (int j = 0; j < 4; ++j)
                bf[j] = *(const short8*)(Bs + (wn + j * 16 + mr) * 64 + kk + quad * 8);
            #pragma unroll
            for (int i = 0; i < 4; ++i)
                #pragma unroll
                for (int j = 0; j < 4; ++j)
                    acc[i][j] = __builtin_amdgcn_mfma_f32_16x16x32_bf16(af[i], bf[j], acc[i][j], 0, 0, 0);
        }
    }
    #pragma unroll
    for (int j = 0; j < 4; ++j) {
        int col = n0 + wn + j * 16 + mr;
        float bs = bias[min(col, V_ - 1)];
        #pragma unroll
        for (int i = 0; i < 4; ++i) {
            int row = m0 + wm + i * 16 + quad * 4;
            #pragma unroll
            for (int ii = 0; ii < 4; ++ii) {
                int r = row + ii;
                if (r < TMAX_ * B_ && col < V_) {
                    int t = r >> 6, b = r & 63;
                    float v = (lens[b] > t) ? (acc[i][j][ii] + bs) : 0.f;
                    preds[((size_t)b * TCAP_ + t) * V_ + col] = v;
                }
            }
        }
    }
}

// ---------------- skinny MFMA GEMM (used once for h0) ----------------
template<int KC>
__global__ void __launch_bounds__(256)
mfma_gemm64(const unsigned short* __restrict__ A, int ld,
            const unsigned short* __restrict__ W,
            const float* __restrict__ bias,
            float* __restrict__ C, unsigned short* __restrict__ Cbf, int ldc)
{
    int wv = threadIdx.x >> 6, lane = threadIdx.x & 63;
    int mr = lane & 15, quad = lane >> 4;
    int m0 = wv * 16;
    int n0 = blockIdx.x * 16;
    const unsigned short* pa = A + (size_t)(m0 + mr) * ld + quad * 8;
    const unsigned short* pb = W + (size_t)(n0 + mr) * ld + quad * 8;
    floatx4 acc = {0.f, 0.f, 0.f, 0.f};
    #pragma unroll 16
    for (int k0 = 0; k0 < KC; k0 += 32) {
        short8 a = *(const short8*)(const void*)(pa + k0);
        short8 b = *(const short8*)(const void*)(pb + k0);
        acc = __builtin_amdgcn_mfma_f32_16x16x32_bf16(a, b, acc, 0, 0, 0);
    }
    int col = n0 + mr;
    float bs = bias ? bias[col] : 0.f;
    #pragma unroll
    for (int i = 0; i < 4; ++i) {
        int row = m0 + quad * 4 + i;
        float v = acc[i] + bs;
        C[(size_t)row * ldc + col] = v;
        if (Cbf) Cbf[(size_t)row * ldc + col] = f2bf_rne(v);
    }
}

// ---------------- fused h-projections: hwh (2048), hf (2048), gh (1536); K=512 ----------------
__global__ void __launch_bounds__(256)
mfma_h3(const unsigned short* __restrict__ hbf,
        const unsigned short* __restrict__ whbf, const float* __restrict__ Wh_b,
        const unsigned short* __restrict__ fbbf, const float* __restrict__ fb_b,
        const unsigned short* __restrict__ ghhbf, const float* __restrict__ ghh_b,
        float* __restrict__ hwh, float* __restrict__ hf, float* __restrict__ gh)
{
    int bt = blockIdx.x;   // 0..351
    const unsigned short* W; const float* bias; float* C; int n0; int ldc;
    if (bt < 128)      { W = whbf;  bias = Wh_b;  C = hwh; n0 = bt * 16;         ldc = E_; }
    else if (bt < 256) { W = fbbf;  bias = fb_b;  C = hf;  n0 = (bt - 128) * 16; ldc = E_; }
    else               { W = ghhbf; bias = ghh_b; C = gh;  n0 = (bt - 256) * 16; ldc = G3_; }
    int wv = threadIdx.x >> 6, lane = threadIdx.x & 63;
    int mr = lane & 15, quad = lane >> 4;
    int m0 = wv * 16;
    const unsigned short* pa = hbf + (size_t)(m0 + mr) * H_ + quad * 8;
    const unsigned short* pb = W + (size_t)(n0 + mr) * H_ + quad * 8;
    floatx4 acc0 = {0.f, 0.f, 0.f, 0.f};
    floatx4 acc1 = {0.f, 0.f, 0.f, 0.f};
    #pragma unroll
    for (int k0 = 0; k0 < 256; k0 += 32) {
        short8 a0 = *(const short8*)(const void*)(pa + k0);
        short8 b0 = *(const short8*)(const void*)(pb + k0);
        acc0 = __builtin_amdgcn_mfma_f32_16x16x32_bf16(a0, b0, acc0, 0, 0, 0);
        short8 a1 = *(const short8*)(const void*)(pa + k0 + 256);
        short8 b1 = *(const short8*)(const void*)(pb + k0 + 256);
        acc1 = __builtin_amdgcn_mfma_f32_16x16x32_bf16(a1, b1, acc1, 0, 0, 0);
    }
    floatx4 acc = acc0 + acc1;
    int col = n0 + mr;
    float bs = bias[col];
    #pragma unroll
    for (int i = 0; i < 4; ++i) {
        int row = m0 + quad * 4 + i;
        C[(size_t)row * ldc + col] = acc[i] + bs;
    }
}

// ---------------- lam: block = (16 p-rows, one b); hwh[b]+Vw staged in LDS ----------------
__global__ void __launch_bounds__(256)
lam_kernel(const unsigned short* __restrict__ xwx, const float* __restrict__ hwh,
           const float* __restrict__ Vw, const float* __restrict__ Vb,
           float* __restrict__ lam)
{
    __shared__ float sh[E_];
    __shared__ float sv[E_];
    int b = blockIdx.y;
    int p0 = blockIdx.x * 16;
    int tid = threadIdx.x;
    {
        const float4* hs = (const float4*)(hwh + (size_t)b * E_);
        const float4* vs = (const float4*)Vw;
        ((float4*)sh)[tid]       = hs[tid];
        ((float4*)sh)[tid + 256] = hs[tid + 256];
        ((float4*)sv)[tid]       = vs[tid];
        ((float4*)sv)[tid + 256] = vs[tid + 256];
    }
    __syncthreads();
    int wv = tid >> 6, lane = tid & 63;
    #pragma unroll
    for (int r = 0; r < 4; ++r) {
        int p = p0 + wv * 4 + r;
        if (p < P_) {
            const unsigned short* px = xwx + ((size_t)b * P_ + p) * E_;
            float acc = 0.f;
            #pragma unroll
            for (int it = 0; it < 4; ++it) {
                int e = it * 512 + lane * 8;
                uint4 u = *(const uint4*)(const void*)(px + e);
                float4 h0 = *(const float4*)(sh + e);
                float4 h1 = *(const float4*)(sh + e + 4);
                float4 v0 = *(const float4*)(sv + e);
                float4 v1 = *(const float4*)(sv + e + 4);
                acc = fmaf(fast_tanh(bf2f(u.x & 0xffffu) + h0.x), v0.x, acc);
                acc = fmaf(fast_tanh(bf2f(u.x >> 16)     + h0.y), v0.y, acc);
                acc = fmaf(fast_tanh(bf2f(u.y & 0xffffu) + h0.z), v0.z, acc);
                acc = fmaf(fast_tanh(bf2f(u.y >> 16)     + h0.w), v0.w, acc);
                acc = fmaf(fast_tanh(bf2f(u.z & 0xffffu) + h1.x), v1.x, acc);
                acc = fmaf(fast_tanh(bf2f(u.z >> 16)     + h1.y), v1.y, acc);
                acc = fmaf(fast_tanh(bf2f(u.w & 0xffffu) + h1.z), v1.z, acc);
                acc = fmaf(fast_tanh(bf2f(u.w >> 16)     + h1.w), v1.w, acc);
            }
            #pragma unroll
            for (int off = 32; off > 0; off >>= 1) acc += __shfl_down(acc, off);
            if (lane == 0) lam[b * P_ + p] = acc + Vb[0];
        }
    }
}

// ---------------- softmax + z + gate + inp(bf16) + alphas ----------------
// grid (5, 64): tiles 0..3 = 512-wide e-chunks (wave-per-p-quarter z), tile 4 = embed.
__global__ void __launch_bounds__(256)
attn_z_kernel(const unsigned short* __restrict__ fbf, const float* __restrict__ lam,
              const float* __restrict__ hf, const float* __restrict__ embed_w,
              const int* __restrict__ captions, const int* __restrict__ lens,
              unsigned short* __restrict__ inpbf, float* __restrict__ alphas, int t)
{
    int b = blockIdx.y;
    int tile = blockIdx.x;
    int tid = threadIdx.x;
    if (tile == 4) {   // embedding -> inp[2048:2560]
        int cap = captions[b * TCAP_ + t];
        const float* e = embed_w + (size_t)cap * EMB_;
        int c = tid * 2;
        float2 v = *(const float2*)(e + c);
        *(unsigned int*)(inpbf + (size_t)b * KI_ + E_ + c) =
            (unsigned)f2bf_rne(v.x) | ((unsigned)f2bf_rne(v.y) << 16);
        return;
    }
    __shared__ float sa[256];
    __shared__ float sr[256];
    __shared__ float psum[4][64][8];   // 8 KB
    float x = (tid < P_) ? lam[b * P_ + tid] : -1e30f;
    sr[tid] = x;
    __syncthreads();
    for (int s = 128; s > 0; s >>= 1) {
        if (tid < s) sr[tid] = fmaxf(sr[tid], sr[tid + s]);
        __syncthreads();
    }
    float mx = sr[0];
    __syncthreads();
    float ex = (tid < P_) ? __expf(x - mx) : 0.f;
    sa[tid] = ex;
    sr[tid] = ex;
    __syncthreads();
    for (int s = 128; s > 0; s >>= 1) {
        if (tid < s) sr[tid] += sr[tid + s];
        __syncthreads();
    }
    float inv = 1.0f / sr[0];
    if (tile == 0 && tid < P_) {
        alphas[(size_t)b * TCAP_ * P_ + (size_t)t * P_ + tid] = (lens[b] > t) ? ex * inv : 0.f;
    }
    // z: wave w covers p in [w*49, w*49+49); lane covers 8 cols at e0+lane*8
    int wv = tid >> 6, lane = tid & 63;
    int e0 = tile * 512;
    const unsigned short* fp = fbf + ((size_t)b * P_ + wv * 49) * E_ + e0 + lane * 8;
    float acc[8] = {0.f,0.f,0.f,0.f,0.f,0.f,0.f,0.f};
    #pragma unroll 7
    for (int i = 0; i < 49; ++i) {
        uint4 u = *(const uint4*)(const void*)(fp + (size_t)i * E_);
        float ap = sa[wv * 49 + i];
        acc[0] = fmaf(ap, bf2f(u.x & 0xffffu), acc[0]);
        acc[1] = fmaf(ap, bf2f(u.x >> 16),     acc[1]);
        acc[2] = fmaf(ap, bf2f(u.y & 0xffffu), acc[2]);
        acc[3] = fmaf(ap, bf2f(u.y >> 16),     acc[3]);
        acc[4] = fmaf(ap, bf2f(u.z & 0xffffu), acc[4]);
        acc[5] = fmaf(ap, bf2f(u.z >> 16),     acc[5]);
        acc[6] = fmaf(ap, bf2f(u.w & 0xffffu), acc[6]);
        acc[7] = fmaf(ap, bf2f(u.w >> 16),     acc[7]);
    }
    #pragma unroll
    for (int k = 0; k < 8; ++k) psum[wv][lane][k] = acc[k];
    __syncthreads();
    int c0 = tid * 2;               // 0..510
    int lc = c0 >> 3, kc = c0 & 7;  // kc even
    float2 s = {0.f, 0.f};
    #pragma unroll
    for (int w2 = 0; w2 < 4; ++w2) {
        float2 v = *(const float2*)&psum[w2][lc][kc];
        s.x += v.x; s.y += v.y;
    }
    s.x *= inv; s.y *= inv;
    float2 gv = *(const float2*)(hf + (size_t)b * E_ + e0 + c0);
    float g0 = fast_sig(gv.x), g1 = fast_sig(gv.y);
    *(unsigned int*)(inpbf + (size_t)b * KI_ + e0 + c0) =
        (unsigned)f2bf_rne(g0 * s.x) | ((unsigned)f2bf_rne(g1 * s.y) << 16);
}

// ---------------- fused gi-GEMM + GRU update ----------------
__global__ void __launch_bounds__(256)
gigru_kernel(const unsigned short* __restrict__ inpbf,
             const unsigned short* __restrict__ wihbf,
             const float* __restrict__ b_ih,
             const float* __restrict__ gh,
             const int* __restrict__ lens,
             float* __restrict__ h, unsigned short* __restrict__ hbf,
             unsigned short* __restrict__ Hall, int t)
{
    __shared__ float red[4][3][16][17];
    int wv = threadIdx.x >> 6, lane = threadIdx.x & 63;
    int mr = lane & 15, quad = lane >> 4;
    int j0 = blockIdx.x * 16;
    int m0 = blockIdx.y * 16;
    int koff = wv * 640;
    const unsigned short* pa = inpbf + (size_t)(m0 + mr) * KI_ + koff + quad * 8;
    const unsigned short* pb0 = wihbf + (size_t)(j0 + mr) * KI_ + koff + quad * 8;
    const unsigned short* pb1 = pb0 + (size_t)512 * KI_;
    const unsigned short* pb2 = pb0 + (size_t)1024 * KI_;
    floatx4 ar = {0.f,0.f,0.f,0.f}, az = {0.f,0.f,0.f,0.f}, an = {0.f,0.f,0.f,0.f};
    #pragma unroll 4
    for (int k0 = 0; k0 < 640; k0 += 32) {
        short8 a = *(const short8*)(const void*)(pa + k0);
        short8 br = *(const short8*)(const void*)(pb0 + k0);
        short8 bz = *(const short8*)(const void*)(pb1 + k0);
        short8 bn = *(const short8*)(const void*)(pb2 + k0);
        ar = __builtin_amdgcn_mfma_f32_16x16x32_bf16(a, br, ar, 0, 0, 0);
        az = __builtin_amdgcn_mfma_f32_16x16x32_bf16(a, bz, az, 0, 0, 0);
        an = __builtin_amdgcn_mfma_f32_16x16x32_bf16(a, bn, an, 0, 0, 0);
    }
    #pragma unroll
    for (int i = 0; i < 4; ++i) {
        red[wv][0][quad * 4 + i][mr] = ar[i];
        red[wv][1][quad * 4 + i][mr] = az[i];
        red[wv][2][quad * 4 + i][mr] = an[i];
    }
    __syncthreads();
    int row = threadIdx.x >> 4, col = threadIdx.x & 15;
    int b = m0 + row, j = j0 + col;
    float ir = red[0][0][row][col] + red[1][0][row][col] + red[2][0][row][col] + red[3][0][row][col] + b_ih[j];
    float iz = red[0][1][row][col] + red[1][1][row][col] + red[2][1][row][col] + red[3][1][row][col] + b_ih[512 + j];
    float in_= red[0][2][row][col] + red[1][2][row][col] + red[2][2][row][col] + red[3][2][row][col] + b_ih[1024 + j];
    float hr = gh[(size_t)b * G3_ + j];
    float hz = gh[(size_t)b * G3_ + 512 + j];
    float hn = gh[(size_t)b * G3_ + 1024 + j];
    float r  = fast_sig(ir + hr);
    float zg = fast_sig(iz + hz);
    float n  = fast_tanh(in_ + r * hn);
    float hp = h[(size_t)b * H_ + j];
    float hv = (1.f - zg) * n + zg * hp;
    float ho = (lens[b] > t) ? hv : hp;
    h[(size_t)b * H_ + j] = ho;
    unsigned short hob = f2bf_rne(ho);
    hbf[(size_t)b * H_ + j] = hob;
    Hall[((size_t)t * B_ + b) * H_ + j] = hob;
}

extern "C" void kernel_launch(void* const* d_in, const int* in_sizes, int n_in,
                              void* d_out, int out_size, void* d_ws, size_t ws_size,
                              hipStream_t stream)
{
    const float* features  = (const float*)d_in[0];
    const int*   captions  = (const int*)d_in[1];
    const int*   lengths   = (const int*)d_in[2];
    const float* Wx_w      = (const float*)d_in[3];
    const float* Wx_b      = (const float*)d_in[4];
    const float* Wh_w      = (const float*)d_in[5];
    const float* Wh_b      = (const float*)d_in[6];
    const float* V_w       = (const float*)d_in[7];
    const float* V_b       = (const float*)d_in[8];
    const float* init_h_w  = (const float*)d_in[9];
    const float* init_h_b  = (const float*)d_in[10];
    const float* f_beta_w  = (const float*)d_in[11];
    const float* f_beta_b  = (const float*)d_in[12];
    const float* embed_w   = (const float*)d_in[13];
    const float* gru_w_ih  = (const float*)d_in[14];
    const float* gru_b_ih  = (const float*)d_in[15];
    const float* gru_w_hh  = (const float*)d_in[16];
    const float* gru_b_hh  = (const float*)d_in[17];
    const float* fc1_w     = (const float*)d_in[18];
    const float* fc1_b     = (const float*)d_in[19];

    float* preds  = (float*)d_out;
    float* alphas = preds + (size_t)B_ * TCAP_ * V_;
    float* dec    = alphas + (size_t)B_ * TCAP_ * P_;

    char* w = (char*)d_ws;
    unsigned short* fbf     = (unsigned short*)w; w += (size_t)12544 * 2048 * 2;
    unsigned short* xwx     = (unsigned short*)w; w += (size_t)12544 * 2048 * 2;
    unsigned short* wxbf    = (unsigned short*)w; w += (size_t)2048 * 2048 * 2;
    unsigned short* whbf    = (unsigned short*)w; w += (size_t)2048 * 512 * 2;
    unsigned short* fbbf    = (unsigned short*)w; w += (size_t)2048 * 512 * 2;
    unsigned short* ghhbf   = (unsigned short*)w; w += (size_t)1536 * 512 * 2;
    unsigned short* wihbf   = (unsigned short*)w; w += (size_t)1536 * 2560 * 2;
    unsigned short* fc1bf   = (unsigned short*)w; w += (size_t)10112 * 512 * 2;  // +slack for OOB tile reads
    unsigned short* ihwbf   = (unsigned short*)w; w += (size_t)512 * 2048 * 2;
    unsigned short* fmeanbf = (unsigned short*)w; w += (size_t)64 * 2048 * 2;
    unsigned short* hbf     = (unsigned short*)w; w += (size_t)64 * 512 * 2;
    unsigned short* inpbf   = (unsigned short*)w; w += (size_t)64 * KI_ * 2;
    unsigned short* Hall    = (unsigned short*)w; w += (size_t)3200 * 512 * 2;   // +slack rows
    float* h   = (float*)w; w += (size_t)64 * 512 * 4;
    float* hwh = (float*)w; w += (size_t)64 * 2048 * 4;
    float* hf  = (float*)w; w += (size_t)64 * 2048 * 4;
    float* gh  = (float*)w; w += (size_t)64 * 1536 * 4;
    float* lam = (float*)w; w += (size_t)64 * 196 * 4;

    init_out_kernel<<<2500, 256, 0, stream>>>(preds, alphas, dec, lengths);

    f2bf_kernel<<<12544, 256, 0, stream>>>(features, fbf, 12544 * 2048 / 8);
    f2bf_kernel<<<2048, 256, 0, stream>>>(Wx_w, wxbf, 2048 * 2048 / 8);
    f2bf_kernel<<<512, 256, 0, stream>>>(Wh_w, whbf, 2048 * 512 / 8);
    f2bf_kernel<<<512, 256, 0, stream>>>(f_beta_w, fbbf, 2048 * 512 / 8);
    f2bf_kernel<<<384, 256, 0, stream>>>(gru_w_hh, ghhbf, 1536 * 512 / 8);
    f2bf_kernel<<<1920, 256, 0, stream>>>(gru_w_ih, wihbf, 1536 * 2560 / 8);
    f2bf_kernel<<<2500, 256, 0, stream>>>(fc1_w, fc1bf, 10000 * 512 / 8);
    f2bf_kernel<<<512, 256, 0, stream>>>(init_h_w, ihwbf, 512 * 2048 / 8);

    mean_kernel<<<512, 256, 0, stream>>>(features, fmeanbf);
    mfma_gemm64<2048><<<32, 256, 0, stream>>>(fmeanbf, 2048, ihwbf, init_h_b, h, hbf, 512);
    mfma_xwx_kernel<<<dim3(16, 98), 256, 0, stream>>>(fbf, wxbf, Wx_b, xwx);

    for (int t = 0; t < TMAX_; ++t) {
        mfma_h3<<<352, 256, 0, stream>>>(hbf, whbf, Wh_b, fbbf, f_beta_b, ghhbf, gru_b_hh,
                                         hwh, hf, gh);
        lam_kernel<<<dim3(13, 64), 256, 0, stream>>>(xwx, hwh, V_w, V_b, lam);
        attn_z_kernel<<<dim3(5, 64), 256, 0, stream>>>(fbf, lam, hf, embed_w, captions,
                                                       lengths, inpbf, alphas, t);
        gigru_kernel<<<dim3(32, 4), 256, 0, stream>>>(inpbf, wihbf, gru_b_ih, gh,
                                                      lengths, h, hbf, Hall, t);
    }
    fc1tile_kernel<<<dim3(79, 25), 256, 0, stream>>>(Hall, fc1bf, fc1_b, preds, lengths);
}